// Round 6
// baseline (2734.863 us; speedup 1.0000x reference)
//
#include <hip/hip_runtime.h>

#define N 512
#define L 8192

#define LOG_MIN -6.907755278982137f
#define LOG_MAX -2.302585092994046f

typedef __attribute__((ext_vector_type(8))) short short8;
typedef __attribute__((ext_vector_type(4))) float f32x4;
typedef __attribute__((ext_vector_type(4))) unsigned int uint4v;

__device__ __forceinline__ float get_delta(const float* logd) {
  float ld = logd[0];
  ld = fminf(fmaxf(ld, LOG_MIN), LOG_MAX);
  return expf(ld);
}
__device__ __forceinline__ unsigned short f2bf(float x) {
  union { float f; unsigned int u; } c; c.f = x;
  unsigned int u = c.u;
  u += 0x7FFFu + ((u >> 16) & 1u);
  return (unsigned short)(u >> 16);
}
__device__ __forceinline__ unsigned int pack2(unsigned short a, unsigned short b) {
  return (unsigned int)a | ((unsigned int)b << 16);
}

// ---------------------------------------------------------------------------
// ws layout (floats):
//   0       kvec (8192)       flat k[t], t = 128q + r  (row-major [64][128])
//   8192    Vt   (512*128)    Vt[n][r] = (Ad^r Bd)[n]
//   73728   W    (64*512)     W[q][:] = C Ad^(128q)
//   106496  B0   (512*512)    U scratch early; squaring ping
//   368640  B1   (512*512)    squaring pong   -> Btab aliases
//   630784  Xi   (512*512)    A1^-1           -> Atab aliases
//   892928  bar  (64 uint)    grid-barrier counters (memset to 0 per call)
// ---------------------------------------------------------------------------

// Device-scope grid barrier (cross-XCD safe: agent-scope atomics + fences).
__device__ __forceinline__ void gsync(unsigned* bar, int p) {
  __syncthreads();
  if (threadIdx.x == 0) {
    __threadfence();
    __hip_atomic_fetch_add(&bar[p], 1u, __ATOMIC_ACQ_REL, __HIP_MEMORY_SCOPE_AGENT);
    while (__hip_atomic_load(&bar[p], __ATOMIC_ACQUIRE, __HIP_MEMORY_SCOPE_AGENT) < 256u)
      __builtin_amdgcn_s_sleep(2);
    __threadfence();
  }
  __syncthreads();
}

// --- phase bodies (all take tid + shared scratch) ---------------------------

// Invert 64x64 diag block of A1 = I - h*A. Columns independent: quad (4 lanes)
// per column, serial over rows, shfl-reduce partial dots. No barriers in loop.
__device__ void diag64(const float* __restrict__ A, float h,
                       float* __restrict__ Xi, int blk, int tid, float* sm) {
  float* Ash = sm;          // [64][65]
  float* xs  = sm + 4160;   // [64][65]
  float* dinv = sm + 8320;  // [64]
  int i0 = blk * 64;
  int r = tid >> 2, c0 = (tid & 3) * 16;
#pragma unroll
  for (int q = 0; q < 16; q += 4) {
    float4 v = *(const float4*)(A + (size_t)(i0 + r) * N + i0 + c0 + q);
    Ash[r * 65 + c0 + q] = v.x; Ash[r * 65 + c0 + q + 1] = v.y;
    Ash[r * 65 + c0 + q + 2] = v.z; Ash[r * 65 + c0 + q + 3] = v.w;
  }
  for (int i = tid; i < 4160; i += 256) xs[i] = 0.f;
  __syncthreads();
  if (tid < 64) dinv[tid] = 1.f / (1.f - h * Ash[tid * 65 + tid]);
  __syncthreads();
  int t = tid >> 2, sub = tid & 3;
  for (int rr = 0; rr < 64; ++rr) {
    if (t <= rr) {
      float s = 0.f;
      for (int k = t + sub; k < rr; k += 4) s += Ash[rr * 65 + k] * xs[k * 65 + t];
      s += __shfl_xor(s, 1, 64);
      s += __shfl_xor(s, 2, 64);
      if (sub == 0)
        xs[rr * 65 + t] = (((rr == t) ? 1.f : 0.f) + h * s) * dinv[rr];
    }
  }
  __syncthreads();
#pragma unroll
  for (int q = 0; q < 16; q += 4) {
    float4 v = {xs[r * 65 + c0 + q], xs[r * 65 + c0 + q + 1],
                xs[r * 65 + c0 + q + 2], xs[r * 65 + c0 + q + 3]};
    *(float4*)(Xi + (size_t)(i0 + r) * N + i0 + c0 + q) = v;
  }
}

// C_ tile (bi,bj of 32) = alpha * A_ * B_ over K.
__device__ void gemm32(const float* __restrict__ A_, int lda,
                       const float* __restrict__ B_, int ldb,
                       float* __restrict__ C_, int ldc,
                       int bi, int bj, int K, float alpha, int tid, float* sm) {
  float* As = sm;
  float* Bs = sm + 1056;
  int tx = tid & 31, ty = tid >> 5;
  float acc[4] = {0.f, 0.f, 0.f, 0.f};
  for (int kb = 0; kb < K; kb += 32) {
#pragma unroll
    for (int m = 0; m < 4; ++m) {
      As[(ty + 8 * m) * 33 + tx] = A_[(size_t)(bi * 32 + ty + 8 * m) * lda + kb + tx];
      Bs[(ty + 8 * m) * 33 + tx] = B_[(size_t)(kb + ty + 8 * m) * ldb + bj * 32 + tx];
    }
    __syncthreads();
#pragma unroll
    for (int kk = 0; kk < 32; ++kk) {
      float bv = Bs[kk * 33 + tx];
#pragma unroll
      for (int m = 0; m < 4; ++m) acc[m] += As[(ty + 8 * m) * 33 + kk] * bv;
    }
    __syncthreads();
  }
#pragma unroll
  for (int m = 0; m < 4; ++m)
    C_[(size_t)(bi * 32 + ty + 8 * m) * ldc + bj * 32 + tx] = alpha * acc[m];
}

// 64x64-tile lower-tri squaring: Q = P*P (first: P := 2*Pin - I on read).
__device__ void sq64(const float* __restrict__ P, float* __restrict__ Q,
                     int bi, int bj, int tid, int first, float* sm) {
  if (bi < bj) {
    int r = tid >> 2, cq = (tid & 3) * 16;
    float4 z = {0.f, 0.f, 0.f, 0.f};
#pragma unroll
    for (int j = 0; j < 4; ++j)
      *(float4*)(Q + (size_t)(bi * 64 + r) * N + bj * 64 + cq + 4 * j) = z;
    return;
  }
  float* Ast = sm;            // [32][68]
  float* Bs = sm + 32 * 68;   // [32][64]
  int tx = tid & 15, ty = tid >> 4;
  float acc[4][4];
#pragma unroll
  for (int i = 0; i < 4; ++i)
#pragma unroll
    for (int j = 0; j < 4; ++j) acc[i][j] = 0.f;
  int ar = tid >> 2, aq = tid & 3;
  int bk = tid >> 3, bc = (tid & 7) * 8;
  for (int kb = bj * 64; kb < (bi + 1) * 64; kb += 32) {
    const float* asrc = P + (size_t)(bi * 64 + ar) * N + kb + aq * 8;
    float av[8];
    *(float4*)&av[0] = *(const float4*)asrc;
    *(float4*)&av[4] = *(const float4*)(asrc + 4);
    const float* bsrc = P + (size_t)(kb + bk) * N + bj * 64 + bc;
    float bv[8];
    *(float4*)&bv[0] = *(const float4*)bsrc;
    *(float4*)&bv[4] = *(const float4*)(bsrc + 4);
    if (first) {
      int gra = bi * 64 + ar, gca = kb + aq * 8;
      int grb = kb + bk, gcb = bj * 64 + bc;
#pragma unroll
      for (int j = 0; j < 8; ++j) {
        av[j] = 2.f * av[j] - ((gra == gca + j) ? 1.f : 0.f);
        bv[j] = 2.f * bv[j] - ((grb == gcb + j) ? 1.f : 0.f);
      }
    }
#pragma unroll
    for (int j = 0; j < 8; ++j) Ast[(aq * 8 + j) * 68 + ar] = av[j];
    *(float4*)&Bs[bk * 64 + bc] = *(float4*)&bv[0];
    *(float4*)&Bs[bk * 64 + bc + 4] = *(float4*)&bv[4];
    __syncthreads();
#pragma unroll 8
    for (int k = 0; k < 32; ++k) {
      float4 a = *(const float4*)&Ast[k * 68 + 4 * ty];
      float4 bb = *(const float4*)&Bs[k * 64 + 4 * tx];
      float ai[4] = {a.x, a.y, a.z, a.w};
      float bj4[4] = {bb.x, bb.y, bb.z, bb.w};
#pragma unroll
      for (int i = 0; i < 4; ++i)
#pragma unroll
        for (int j = 0; j < 4; ++j) acc[i][j] = fmaf(ai[i], bj4[j], acc[i][j]);
    }
    __syncthreads();
  }
#pragma unroll
  for (int i = 0; i < 4; ++i) {
    float4 v = {acc[i][0], acc[i][1], acc[i][2], acc[i][3]};
    *(float4*)(Q + (size_t)(bi * 64 + 4 * ty + i) * N + bj * 64 + 4 * tx) = v;
  }
}

// Vt[:, base+c] = (first ? 2P-I : P) * Vt[:, c], c < base. Tiled GEMM.
__device__ void vstep_g(const float* __restrict__ P, float* __restrict__ Vt,
                        int base, int first, int idx, int tid, float* sm) {
  int bi = idx & 15, cj = idx >> 4;
  float* As = sm;
  float* Bs = sm + 1056;
  int tx = tid & 31, ty = tid >> 5;
  float acc[4] = {0.f, 0.f, 0.f, 0.f};
  int kmax = (bi + 1) * 32;
  for (int kb = 0; kb < kmax; kb += 32) {
#pragma unroll
    for (int m = 0; m < 4; ++m) {
      int row = bi * 32 + ty + 8 * m;
      float a = P[(size_t)row * N + kb + tx];
      if (first) a = 2.f * a - ((row == kb + tx) ? 1.f : 0.f);
      As[(ty + 8 * m) * 33 + tx] = a;
      Bs[(ty + 8 * m) * 33 + tx] = Vt[(size_t)(kb + ty + 8 * m) * 128 + cj * 32 + tx];
    }
    __syncthreads();
#pragma unroll
    for (int kk = 0; kk < 32; ++kk) {
      float bv = Bs[kk * 33 + tx];
#pragma unroll
      for (int m = 0; m < 4; ++m) acc[m] += As[(ty + 8 * m) * 33 + kk] * bv;
    }
    __syncthreads();
  }
  int c = cj * 32 + tx;
  if (c < base) {
#pragma unroll
    for (int m = 0; m < 4; ++m)
      Vt[(size_t)(bi * 32 + ty + 8 * m) * 128 + base + c] = acc[m];
  }
}

// W[base+q][:] = W[q][:] * P, q < base. Column tile cj.
__device__ void wstep_g(const float* __restrict__ P, float* __restrict__ W,
                        int base, int cj, int tid, float* sm) {
  float* As = sm;
  float* Bs = sm + 1056;
  int tx = tid & 31, ty = tid >> 5;
  float acc[4] = {0.f, 0.f, 0.f, 0.f};
  for (int kb = 0; kb < N; kb += 32) {
#pragma unroll
    for (int m = 0; m < 4; ++m) {
      As[(ty + 8 * m) * 33 + tx] = W[(size_t)(ty + 8 * m) * N + kb + tx];
      Bs[(ty + 8 * m) * 33 + tx] = P[(size_t)(kb + ty + 8 * m) * N + cj * 32 + tx];
    }
    __syncthreads();
#pragma unroll
    for (int kk = 0; kk < 32; ++kk) {
      float bv = Bs[kk * 33 + tx];
#pragma unroll
      for (int m = 0; m < 4; ++m) acc[m] += As[(ty + 8 * m) * 33 + kk] * bv;
    }
    __syncthreads();
  }
#pragma unroll
  for (int m = 0; m < 4; ++m) {
    int q = ty + 8 * m;
    if (q < base) W[(size_t)(base + q) * N + cj * 32 + tx] = acc[m];
  }
}

// Vt[:,0] = delta * Xi * Bm: 4 rows per block (one per wave).
__device__ void bd1_body(const float* __restrict__ Xi, const float* __restrict__ Bm,
                         float delta, float* __restrict__ Vt, int blk, int tid,
                         float* sm) {
  float* bs = sm;
  if (tid < 128) ((float4*)bs)[tid] = ((const float4*)Bm)[tid];
  __syncthreads();
  int w = tid >> 6, lane = tid & 63;
  int row = blk * 4 + w;
  const float* Xr = Xi + (size_t)row * N + lane * 8;
  float4 a0 = *(const float4*)Xr;
  float4 a1 = *(const float4*)(Xr + 4);
  const float* bp = bs + lane * 8;
  float acc = a0.x * bp[0] + a0.y * bp[1] + a0.z * bp[2] + a0.w * bp[3]
            + a1.x * bp[4] + a1.y * bp[5] + a1.z * bp[6] + a1.w * bp[7];
  acc += __shfl_xor(acc, 1, 64);
  acc += __shfl_xor(acc, 2, 64);
  acc += __shfl_xor(acc, 4, 64);
  acc += __shfl_xor(acc, 8, 64);
  acc += __shfl_xor(acc, 16, 64);
  acc += __shfl_xor(acc, 32, 64);
  if (lane == 0) Vt[(size_t)row * 128] = delta * acc;
}

// --- the fused serial chain: 22 phases, one kernel -------------------------
__global__ __launch_bounds__(256, 2) void k_chain(
    const float* __restrict__ A, const float* __restrict__ Bm,
    const float* __restrict__ C, const float* __restrict__ logd,
    float* __restrict__ Xi, float* __restrict__ B0, float* __restrict__ B1,
    float* __restrict__ Vt, float* __restrict__ W, float* __restrict__ kvec,
    unsigned* bar) {
  __shared__ float sm[8704];
  int b = blockIdx.x, tid = threadIdx.x;
  float delta = get_delta(logd);
  float h = 0.5f * delta;
  float* U = B0;

  // PH0: diag inverses + zero strict-upper 64-tiles + W[0]=C
  if (b < 8) {
    diag64(A, h, Xi, b, tid, sm);
  } else if (b < 36) {
    int idx = b - 8, bi = 0, bj = 0, cnt = 0;
    for (int i = 0; i < 8; ++i)
      for (int j = i + 1; j < 8; ++j) { if (cnt == idx) { bi = i; bj = j; } ++cnt; }
    int r = tid >> 2, c0 = (tid & 3) * 16;
    float4 z = {0.f, 0.f, 0.f, 0.f};
#pragma unroll
    for (int q = 0; q < 16; q += 4)
      *(float4*)(Xi + (size_t)(bi * 64 + r) * N + bj * 64 + c0 + q) = z;
  } else if (b == 36) {
    for (int i = tid; i < N; i += 256) W[i] = C[i];
  }
  gsync(bar, 0);
  // PH1/PH2: level 64 -> 128
  if (b < 16) {
    int g = b >> 2, t = b & 3;
    gemm32(A + (size_t)(128 * g + 64) * N + 128 * g, N,
           Xi + (size_t)(128 * g) * (N + 1), N,
           U + g * 4096, 64, t >> 1, t & 1, 64, 1.0f, tid, sm);
  }
  gsync(bar, 1);
  if (b < 16) {
    int g = b >> 2, t = b & 3;
    gemm32(Xi + (size_t)(128 * g + 64) * (N + 1), N, U + g * 4096, 64,
           Xi + (size_t)(128 * g + 64) * N + 128 * g, N, t >> 1, t & 1, 64, h, tid, sm);
  }
  gsync(bar, 2);
  // PH3/PH4: level 128 -> 256
  if (b < 32) {
    int g = b >> 4, t = b & 15;
    gemm32(A + (size_t)(256 * g + 128) * N + 256 * g, N,
           Xi + (size_t)(256 * g) * (N + 1), N,
           U + g * 16384, 128, t >> 2, t & 3, 128, 1.0f, tid, sm);
  }
  gsync(bar, 3);
  if (b < 32) {
    int g = b >> 4, t = b & 15;
    gemm32(Xi + (size_t)(256 * g + 128) * (N + 1), N, U + g * 16384, 128,
           Xi + (size_t)(256 * g + 128) * N + 256 * g, N, t >> 2, t & 3, 128, h, tid, sm);
  }
  gsync(bar, 4);
  // PH5/PH6: level 256 -> 512
  if (b < 64)
    gemm32(A + (size_t)256 * N, N, Xi, N, U, 256, b >> 3, b & 7, 256, 1.0f, tid, sm);
  gsync(bar, 5);
  if (b < 64)
    gemm32(Xi + (size_t)256 * (N + 1), N, U, 256,
           Xi + (size_t)256 * N, N, b >> 3, b & 7, 256, h, tid, sm);
  gsync(bar, 6);
  // PH7: Bd
  if (b < 128) bd1_body(Xi, Bm, delta, Vt, b, tid, sm);
  gsync(bar, 7);
  // PH8..PH14: squaring + V doubling  (Ad = 2*Xi - I read-transform at PH8)
  if (b < 64) sq64(Xi, B1, b >> 3, b & 7, tid, 1, sm);
  else if (b < 80) vstep_g(Xi, Vt, 1, 1, b - 64, tid, sm);
  gsync(bar, 8);
  if (b < 64) sq64(B1, B0, b >> 3, b & 7, tid, 0, sm);
  else if (b < 80) vstep_g(B1, Vt, 2, 0, b - 64, tid, sm);
  gsync(bar, 9);
  if (b < 64) sq64(B0, B1, b >> 3, b & 7, tid, 0, sm);
  else if (b < 80) vstep_g(B0, Vt, 4, 0, b - 64, tid, sm);
  gsync(bar, 10);
  if (b < 64) sq64(B1, B0, b >> 3, b & 7, tid, 0, sm);
  else if (b < 80) vstep_g(B1, Vt, 8, 0, b - 64, tid, sm);
  gsync(bar, 11);
  if (b < 64) sq64(B0, B1, b >> 3, b & 7, tid, 0, sm);
  else if (b < 80) vstep_g(B0, Vt, 16, 0, b - 64, tid, sm);
  gsync(bar, 12);
  if (b < 64) sq64(B1, B0, b >> 3, b & 7, tid, 0, sm);
  else if (b < 80) vstep_g(B1, Vt, 32, 0, b - 64, tid, sm);
  gsync(bar, 13);
  if (b < 64) sq64(B0, B1, b >> 3, b & 7, tid, 0, sm);
  else if (b < 96) vstep_g(B0, Vt, 64, 0, b - 64, tid, sm);
  gsync(bar, 14);
  // PH15..PH19: squaring + W doubling
  if (b < 64) sq64(B1, B0, b >> 3, b & 7, tid, 0, sm);
  else if (b < 80) wstep_g(B1, W, 1, b - 64, tid, sm);
  gsync(bar, 15);
  if (b < 64) sq64(B0, B1, b >> 3, b & 7, tid, 0, sm);
  else if (b < 80) wstep_g(B0, W, 2, b - 64, tid, sm);
  gsync(bar, 16);
  if (b < 64) sq64(B1, B0, b >> 3, b & 7, tid, 0, sm);
  else if (b < 80) wstep_g(B1, W, 4, b - 64, tid, sm);
  gsync(bar, 17);
  if (b < 64) sq64(B0, B1, b >> 3, b & 7, tid, 0, sm);
  else if (b < 80) wstep_g(B0, W, 8, b - 64, tid, sm);
  gsync(bar, 18);
  if (b < 64) sq64(B1, B0, b >> 3, b & 7, tid, 0, sm);
  else if (b < 80) wstep_g(B1, W, 16, b - 64, tid, sm);
  gsync(bar, 19);
  // PH20: last W doubling (P = B0 = Ad^4096)
  if (b < 16) wstep_g(B0, W, 32, b, tid, sm);
  gsync(bar, 20);
  // PH21: kvec = W * Vt
  if (b < 8)
    gemm32(W, N, Vt, 128, kvec, 128, b >> 2, b & 3, N, 1.0f, tid, sm);
}

// Fused: blocks 0-255 -> X A-frags; blocks 256-383 -> Toeplitz B-frags.
__global__ __launch_bounds__(256) void k_frag(const float* __restrict__ X,
                                              const float* __restrict__ kvec,
                                              unsigned int* __restrict__ Atab,
                                              unsigned int* __restrict__ Btab) {
  int bx = blockIdx.x;
  if (bx < 256) {
    int tid = bx * 256 + threadIdx.x;
    int lane = tid & 63;
    int f = tid >> 6;
    int bt = f >> 8, ut = f & 255;
    int row = bt * 16 + (lane & 15);
    int u0 = ut * 32 + ((lane >> 4) << 3);
    const float* xp = X + (size_t)row * L + u0;
    unsigned short v[8];
#pragma unroll
    for (int e = 0; e < 8; ++e) v[e] = f2bf(xp[e]);
    uint4v o;
    o.x = pack2(v[0], v[1]); o.y = pack2(v[2], v[3]);
    o.z = pack2(v[4], v[5]); o.w = pack2(v[6], v[7]);
    ((uint4v*)Atab)[(size_t)f * 64 + lane] = o;
  } else {
    int tid = (bx - 256) * 256 + threadIdx.x;
    int lane = tid & 63;
    int si = tid >> 6;
    int base = si * 16 + (lane & 15) - ((lane >> 4) << 3);
    unsigned short v[8];
#pragma unroll
    for (int e = 0; e < 8; ++e) {
      int idx = base - e;
      float x = (idx >= 0) ? kvec[idx] : 0.0f;
      v[e] = f2bf(x);
    }
    uint4v o;
    o.x = pack2(v[0], v[1]); o.y = pack2(v[2], v[3]);
    o.z = pack2(v[4], v[5]); o.w = pack2(v[6], v[7]);
    ((uint4v*)Btab)[(size_t)si * 64 + lane] = o;
  }
}

// Y = X * Toeplitz + D*X. Block p handles t-tile pair (p, 511-p): balanced.
// 4 waves = 4 batch tiles; B-frags LDS-staged per 16-step chunk (shared x4).
__global__ __launch_bounds__(256) void k_convmm(const short8* __restrict__ Atab,
                                                const short8* __restrict__ Btab,
                                                const float* __restrict__ X,
                                                const float* __restrict__ Dp,
                                                float* __restrict__ Y) {
  __shared__ short8 bsh[32][64];
  int tid = threadIdx.x, lane = tid & 63, bt = tid >> 6;
  int p = blockIdx.x;
  int jL = p, jH = 511 - p;
  int nL = (jL + 2) >> 1, nH = (jH + 2) >> 1;
  f32x4 aL = {0.f, 0.f, 0.f, 0.f}, aH = {0.f, 0.f, 0.f, 0.f};
  const short8* Abase = Atab + (size_t)bt * 256 * 64 + lane;
  for (int u0 = 0; u0 < nH; u0 += 16) {
#pragma unroll
    for (int k = 0; k < 8; ++k) {
      int idx = tid + 256 * k;          // 0..2047
      int f = idx >> 6, ln = idx & 63;
      int i = f & 15;
      int ut = u0 + i;
      if (f < 16) {
        if (ut < nH) bsh[i][ln] = Btab[(size_t)(jH - 2 * ut) * 64 + ln];
      } else {
        if (ut < nL) bsh[16 + i][ln] = Btab[(size_t)(jL - 2 * ut) * 64 + ln];
      }
    }
    __syncthreads();
    int m = (nH - u0 < 16) ? (nH - u0) : 16;
    for (int i = 0; i < m; ++i) {
      short8 a = Abase[(size_t)(u0 + i) * 64];
      aH = __builtin_amdgcn_mfma_f32_16x16x32_bf16(a, bsh[i][lane], aH, 0, 0, 0);
      if (u0 + i < nL)
        aL = __builtin_amdgcn_mfma_f32_16x16x32_bf16(a, bsh[16 + i][lane], aL, 0, 0, 0);
    }
    __syncthreads();
  }
  float D0 = Dp[0];
  int tt = lane & 15, rq = (lane >> 4) << 2;
#pragma unroll
  for (int r = 0; r < 4; ++r) {
    int bb = bt * 16 + rq + r;
    size_t oL = (size_t)bb * L + jL * 16 + tt;
    size_t oH = (size_t)bb * L + jH * 16 + tt;
    Y[oL] = aL[r] + D0 * X[oL];
    Y[oH] = aH[r] + D0 * X[oH];
  }
}

extern "C" void kernel_launch(void* const* d_in, const int* in_sizes, int n_in,
                              void* d_out, int out_size, void* d_ws, size_t ws_size,
                              hipStream_t stream) {
  const float* X  = (const float*)d_in[0];
  const float* A  = (const float*)d_in[1];
  const float* Bm = (const float*)d_in[2];
  const float* C  = (const float*)d_in[3];
  const float* D  = (const float*)d_in[4];
  const float* ld = (const float*)d_in[5];
  float* Y = (float*)d_out;

  float* ws = (float*)d_ws;
  float* kv = ws;                  // 8192
  float* Vt = ws + 8192;           // 512*128
  float* W  = ws + 73728;          // 64*512
  float* B0 = ws + 106496;         // 512*512 (U scratch / ping)
  float* B1 = ws + 368640;         // 512*512 (pong)
  float* Xi = ws + 630784;         // 512*512 (A1inv)
  unsigned* bar = (unsigned*)(ws + 892928);

  unsigned int* Atab = (unsigned int*)Xi;  // Xi dead after PH8
  unsigned int* Btab = (unsigned int*)B1;  // B1 dead after PH19

  hipMemsetAsync(bar, 0, 64 * sizeof(unsigned), stream);
  k_chain<<<256, 256, 0, stream>>>(A, Bm, C, ld, Xi, B0, B1, Vt, W, kv, bar);
  k_frag<<<384, 256, 0, stream>>>(X, kv, Atab, Btab);
  k_convmm<<<256, 256, 0, stream>>>((const short8*)Atab, (const short8*)Btab, X, D, Y);
}

// Round 7
// 1018.445 us; speedup vs baseline: 2.6853x; 2.6853x over previous
//
#include <hip/hip_runtime.h>

#define N 512
#define L 8192

#define LOG_MIN -6.907755278982137f
#define LOG_MAX -2.302585092994046f

typedef __attribute__((ext_vector_type(8))) short short8;
typedef __attribute__((ext_vector_type(4))) float f32x4;
typedef __attribute__((ext_vector_type(4))) unsigned int uint4v;

__device__ __forceinline__ float get_delta(const float* logd) {
  float ld = logd[0];
  ld = fminf(fmaxf(ld, LOG_MIN), LOG_MAX);
  return expf(ld);
}
__device__ __forceinline__ unsigned short f2bf(float x) {
  union { float f; unsigned int u; } c; c.f = x;
  unsigned int u = c.u;
  u += 0x7FFFu + ((u >> 16) & 1u);
  return (unsigned short)(u >> 16);
}
__device__ __forceinline__ unsigned int pack2(unsigned short a, unsigned short b) {
  return (unsigned int)a | ((unsigned int)b << 16);
}

// ---------------------------------------------------------------------------
// ws layout (floats):
//   0        kvec (8192)
//   8192     Vt   (512*128)
//   73728    W    (64*512)
//   106496   B0   (512*512)   U scratch / squaring ping
//   368640   B1   (512*512)   squaring pong
//   630784   Xi   (512*512)   A1^-1
//   892928   bar  (64 uint)
//   958464   Atab (262144 f = 1MB bf16 A-frags)
//   1220608  Btab (131072 f = 512KB bf16 B-frags)
// ---------------------------------------------------------------------------

// Grid barrier: RELAXED polling (no per-poll cache invalidate!), one
// release fence before signal, one acquire fence after the count is full.
__device__ __forceinline__ void gsync(unsigned* bar, int p) {
  __syncthreads();
  if (threadIdx.x == 0) {
    __builtin_amdgcn_fence(__ATOMIC_RELEASE, "agent");
    __hip_atomic_fetch_add(&bar[p], 1u, __ATOMIC_RELAXED, __HIP_MEMORY_SCOPE_AGENT);
    while (__hip_atomic_load(&bar[p], __ATOMIC_RELAXED, __HIP_MEMORY_SCOPE_AGENT) < 256u)
      __builtin_amdgcn_s_sleep(8);
    __builtin_amdgcn_fence(__ATOMIC_ACQUIRE, "agent");
  }
  __syncthreads();
}

// --- phase bodies -----------------------------------------------------------

__device__ void diag64(const float* __restrict__ A, float h,
                       float* __restrict__ Xi, int blk, int tid, float* sm) {
  float* Ash = sm;          // [64][65]
  float* xs  = sm + 4160;   // [64][65]
  float* dinv = sm + 8320;  // [64]
  int i0 = blk * 64;
  int r = tid >> 2, c0 = (tid & 3) * 16;
#pragma unroll
  for (int q = 0; q < 16; q += 4) {
    float4 v = *(const float4*)(A + (size_t)(i0 + r) * N + i0 + c0 + q);
    Ash[r * 65 + c0 + q] = v.x; Ash[r * 65 + c0 + q + 1] = v.y;
    Ash[r * 65 + c0 + q + 2] = v.z; Ash[r * 65 + c0 + q + 3] = v.w;
  }
  for (int i = tid; i < 4160; i += 256) xs[i] = 0.f;
  __syncthreads();
  if (tid < 64) dinv[tid] = 1.f / (1.f - h * Ash[tid * 65 + tid]);
  __syncthreads();
  int t = tid >> 2, sub = tid & 3;
  for (int rr = 0; rr < 64; ++rr) {
    if (t <= rr) {
      float s = 0.f;
      for (int k = t + sub; k < rr; k += 4) s += Ash[rr * 65 + k] * xs[k * 65 + t];
      s += __shfl_xor(s, 1, 64);
      s += __shfl_xor(s, 2, 64);
      if (sub == 0)
        xs[rr * 65 + t] = (((rr == t) ? 1.f : 0.f) + h * s) * dinv[rr];
    }
  }
  __syncthreads();
#pragma unroll
  for (int q = 0; q < 16; q += 4) {
    float4 v = {xs[r * 65 + c0 + q], xs[r * 65 + c0 + q + 1],
                xs[r * 65 + c0 + q + 2], xs[r * 65 + c0 + q + 3]};
    *(float4*)(Xi + (size_t)(i0 + r) * N + i0 + c0 + q) = v;
  }
}

__device__ void gemm32(const float* __restrict__ A_, int lda,
                       const float* __restrict__ B_, int ldb,
                       float* __restrict__ C_, int ldc,
                       int bi, int bj, int K, float alpha, int tid, float* sm) {
  float* As = sm;
  float* Bs = sm + 1056;
  int tx = tid & 31, ty = tid >> 5;
  float acc[4] = {0.f, 0.f, 0.f, 0.f};
  for (int kb = 0; kb < K; kb += 32) {
#pragma unroll
    for (int m = 0; m < 4; ++m) {
      As[(ty + 8 * m) * 33 + tx] = A_[(size_t)(bi * 32 + ty + 8 * m) * lda + kb + tx];
      Bs[(ty + 8 * m) * 33 + tx] = B_[(size_t)(kb + ty + 8 * m) * ldb + bj * 32 + tx];
    }
    __syncthreads();
#pragma unroll
    for (int kk = 0; kk < 32; ++kk) {
      float bv = Bs[kk * 33 + tx];
#pragma unroll
      for (int m = 0; m < 4; ++m) acc[m] += As[(ty + 8 * m) * 33 + kk] * bv;
    }
    __syncthreads();
  }
#pragma unroll
  for (int m = 0; m < 4; ++m)
    C_[(size_t)(bi * 32 + ty + 8 * m) * ldc + bj * 32 + tx] = alpha * acc[m];
}

__device__ void sq64(const float* __restrict__ P, float* __restrict__ Q,
                     int bi, int bj, int tid, int first, float* sm) {
  if (bi < bj) {
    int r = tid >> 2, cq = (tid & 3) * 16;
    float4 z = {0.f, 0.f, 0.f, 0.f};
#pragma unroll
    for (int j = 0; j < 4; ++j)
      *(float4*)(Q + (size_t)(bi * 64 + r) * N + bj * 64 + cq + 4 * j) = z;
    return;
  }
  float* Ast = sm;            // [32][68]
  float* Bs = sm + 32 * 68;   // [32][64]
  int tx = tid & 15, ty = tid >> 4;
  float acc[4][4];
#pragma unroll
  for (int i = 0; i < 4; ++i)
#pragma unroll
    for (int j = 0; j < 4; ++j) acc[i][j] = 0.f;
  int ar = tid >> 2, aq = tid & 3;
  int bk = tid >> 3, bc = (tid & 7) * 8;
  for (int kb = bj * 64; kb < (bi + 1) * 64; kb += 32) {
    const float* asrc = P + (size_t)(bi * 64 + ar) * N + kb + aq * 8;
    float av[8];
    *(float4*)&av[0] = *(const float4*)asrc;
    *(float4*)&av[4] = *(const float4*)(asrc + 4);
    const float* bsrc = P + (size_t)(kb + bk) * N + bj * 64 + bc;
    float bv[8];
    *(float4*)&bv[0] = *(const float4*)bsrc;
    *(float4*)&bv[4] = *(const float4*)(bsrc + 4);
    if (first) {
      int gra = bi * 64 + ar, gca = kb + aq * 8;
      int grb = kb + bk, gcb = bj * 64 + bc;
#pragma unroll
      for (int j = 0; j < 8; ++j) {
        av[j] = 2.f * av[j] - ((gra == gca + j) ? 1.f : 0.f);
        bv[j] = 2.f * bv[j] - ((grb == gcb + j) ? 1.f : 0.f);
      }
    }
#pragma unroll
    for (int j = 0; j < 8; ++j) Ast[(aq * 8 + j) * 68 + ar] = av[j];
    *(float4*)&Bs[bk * 64 + bc] = *(float4*)&bv[0];
    *(float4*)&Bs[bk * 64 + bc + 4] = *(float4*)&bv[4];
    __syncthreads();
#pragma unroll 8
    for (int k = 0; k < 32; ++k) {
      float4 a = *(const float4*)&Ast[k * 68 + 4 * ty];
      float4 bb = *(const float4*)&Bs[k * 64 + 4 * tx];
      float ai[4] = {a.x, a.y, a.z, a.w};
      float bj4[4] = {bb.x, bb.y, bb.z, bb.w};
#pragma unroll
      for (int i = 0; i < 4; ++i)
#pragma unroll
        for (int j = 0; j < 4; ++j) acc[i][j] = fmaf(ai[i], bj4[j], acc[i][j]);
    }
    __syncthreads();
  }
#pragma unroll
  for (int i = 0; i < 4; ++i) {
    float4 v = {acc[i][0], acc[i][1], acc[i][2], acc[i][3]};
    *(float4*)(Q + (size_t)(bi * 64 + 4 * ty + i) * N + bj * 64 + 4 * tx) = v;
  }
}

__device__ void vstep_g(const float* __restrict__ P, float* __restrict__ Vt,
                        int base, int first, int idx, int tid, float* sm) {
  int bi = idx & 15, cj = idx >> 4;
  float* As = sm;
  float* Bs = sm + 1056;
  int tx = tid & 31, ty = tid >> 5;
  float acc[4] = {0.f, 0.f, 0.f, 0.f};
  int kmax = (bi + 1) * 32;
  for (int kb = 0; kb < kmax; kb += 32) {
#pragma unroll
    for (int m = 0; m < 4; ++m) {
      int row = bi * 32 + ty + 8 * m;
      float a = P[(size_t)row * N + kb + tx];
      if (first) a = 2.f * a - ((row == kb + tx) ? 1.f : 0.f);
      As[(ty + 8 * m) * 33 + tx] = a;
      Bs[(ty + 8 * m) * 33 + tx] = Vt[(size_t)(kb + ty + 8 * m) * 128 + cj * 32 + tx];
    }
    __syncthreads();
#pragma unroll
    for (int kk = 0; kk < 32; ++kk) {
      float bv = Bs[kk * 33 + tx];
#pragma unroll
      for (int m = 0; m < 4; ++m) acc[m] += As[(ty + 8 * m) * 33 + kk] * bv;
    }
    __syncthreads();
  }
  int c = cj * 32 + tx;
  if (c < base) {
#pragma unroll
    for (int m = 0; m < 4; ++m)
      Vt[(size_t)(bi * 32 + ty + 8 * m) * 128 + base + c] = acc[m];
  }
}

__device__ void wstep_g(const float* __restrict__ P, float* __restrict__ W,
                        int base, int cj, int tid, float* sm) {
  float* As = sm;
  float* Bs = sm + 1056;
  int tx = tid & 31, ty = tid >> 5;
  float acc[4] = {0.f, 0.f, 0.f, 0.f};
  for (int kb = 0; kb < N; kb += 32) {
#pragma unroll
    for (int m = 0; m < 4; ++m) {
      As[(ty + 8 * m) * 33 + tx] = W[(size_t)(ty + 8 * m) * N + kb + tx];
      Bs[(ty + 8 * m) * 33 + tx] = P[(size_t)(kb + ty + 8 * m) * N + cj * 32 + tx];
    }
    __syncthreads();
#pragma unroll
    for (int kk = 0; kk < 32; ++kk) {
      float bv = Bs[kk * 33 + tx];
#pragma unroll
      for (int m = 0; m < 4; ++m) acc[m] += As[(ty + 8 * m) * 33 + kk] * bv;
    }
    __syncthreads();
  }
#pragma unroll
  for (int m = 0; m < 4; ++m) {
    int q = ty + 8 * m;
    if (q < base) W[(size_t)(base + q) * N + cj * 32 + tx] = acc[m];
  }
}

__device__ void bd1_body(const float* __restrict__ Xi, const float* __restrict__ Bm,
                         float delta, float* __restrict__ Vt, int blk, int tid,
                         float* sm) {
  float* bs = sm;
  if (tid < 128) ((float4*)bs)[tid] = ((const float4*)Bm)[tid];
  __syncthreads();
  int w = tid >> 6, lane = tid & 63;
  int row = blk * 4 + w;
  const float* Xr = Xi + (size_t)row * N + lane * 8;
  float4 a0 = *(const float4*)Xr;
  float4 a1 = *(const float4*)(Xr + 4);
  const float* bp = bs + lane * 8;
  float acc = a0.x * bp[0] + a0.y * bp[1] + a0.z * bp[2] + a0.w * bp[3]
            + a1.x * bp[4] + a1.y * bp[5] + a1.z * bp[6] + a1.w * bp[7];
  acc += __shfl_xor(acc, 1, 64);
  acc += __shfl_xor(acc, 2, 64);
  acc += __shfl_xor(acc, 4, 64);
  acc += __shfl_xor(acc, 8, 64);
  acc += __shfl_xor(acc, 16, 64);
  acc += __shfl_xor(acc, 32, 64);
  if (lane == 0) Vt[(size_t)row * 128] = delta * acc;
}

// X -> bf16 A-frag unit u (u in [0, 65536))
__device__ __forceinline__ void afrag_unit(const float* __restrict__ X,
                                           unsigned int* __restrict__ Atab, int u) {
  int lane = u & 63;
  int f = u >> 6;
  int bt = f >> 8, ut = f & 255;
  int row = bt * 16 + (lane & 15);
  int u0 = ut * 32 + ((lane >> 4) << 3);
  const float* xp = X + (size_t)row * L + u0;
  unsigned short v[8];
#pragma unroll
  for (int e = 0; e < 8; ++e) v[e] = f2bf(xp[e]);
  uint4v o;
  o.x = pack2(v[0], v[1]); o.y = pack2(v[2], v[3]);
  o.z = pack2(v[4], v[5]); o.w = pack2(v[6], v[7]);
  ((uint4v*)Atab)[(size_t)f * 64 + lane] = o;
}

// kvec -> bf16 B-frag unit u (u in [0, 32768))
__device__ __forceinline__ void bfrag_unit(const float* __restrict__ kvec,
                                           unsigned int* __restrict__ Btab, int u) {
  int lane = u & 63;
  int si = u >> 6;
  int base = si * 16 + (lane & 15) - ((lane >> 4) << 3);
  unsigned short v[8];
#pragma unroll
  for (int e = 0; e < 8; ++e) {
    int idx = base - e;
    float x = (idx >= 0) ? kvec[idx] : 0.0f;
    v[e] = f2bf(x);
  }
  uint4v o;
  o.x = pack2(v[0], v[1]); o.y = pack2(v[2], v[3]);
  o.z = pack2(v[4], v[5]); o.w = pack2(v[6], v[7]);
  ((uint4v*)Btab)[(size_t)si * 64 + lane] = o;
}

// --- fused serial chain: 23 phases, one kernel -----------------------------
__global__ __launch_bounds__(256, 2) void k_chain(
    const float* __restrict__ A, const float* __restrict__ Bm,
    const float* __restrict__ C, const float* __restrict__ logd,
    const float* __restrict__ X,
    float* __restrict__ Xi, float* __restrict__ B0, float* __restrict__ B1,
    float* __restrict__ Vt, float* __restrict__ W, float* __restrict__ kvec,
    unsigned int* __restrict__ Atab, unsigned int* __restrict__ Btab,
    unsigned* bar) {
  __shared__ float sm[8704];
  int b = blockIdx.x, tid = threadIdx.x;
  float delta = get_delta(logd);
  float h = 0.5f * delta;
  float* U = B0;

  // PH0: diag inverses + zero strict-upper + W[0]=C + Atab fill (idle blocks)
  if (b < 8) {
    diag64(A, h, Xi, b, tid, sm);
  } else if (b < 36) {
    int idx = b - 8, bi = 0, bj = 0, cnt = 0;
    for (int i = 0; i < 8; ++i)
      for (int j = i + 1; j < 8; ++j) { if (cnt == idx) { bi = i; bj = j; } ++cnt; }
    int r = tid >> 2, c0 = (tid & 3) * 16;
    float4 z = {0.f, 0.f, 0.f, 0.f};
#pragma unroll
    for (int q = 0; q < 16; q += 4)
      *(float4*)(Xi + (size_t)(bi * 64 + r) * N + bj * 64 + c0 + q) = z;
  } else if (b == 36) {
    for (int i = tid; i < N; i += 256) W[i] = C[i];
  } else if (b >= 128) {
    int base = (b - 128) * 512;
    afrag_unit(X, Atab, base + tid);
    afrag_unit(X, Atab, base + 256 + tid);
  }
  gsync(bar, 0);
  // PH1/PH2: level 64 -> 128
  if (b < 16) {
    int g = b >> 2, t = b & 3;
    gemm32(A + (size_t)(128 * g + 64) * N + 128 * g, N,
           Xi + (size_t)(128 * g) * (N + 1), N,
           U + g * 4096, 64, t >> 1, t & 1, 64, 1.0f, tid, sm);
  }
  gsync(bar, 1);
  if (b < 16) {
    int g = b >> 2, t = b & 3;
    gemm32(Xi + (size_t)(128 * g + 64) * (N + 1), N, U + g * 4096, 64,
           Xi + (size_t)(128 * g + 64) * N + 128 * g, N, t >> 1, t & 1, 64, h, tid, sm);
  }
  gsync(bar, 2);
  // PH3/PH4: level 128 -> 256
  if (b < 32) {
    int g = b >> 4, t = b & 15;
    gemm32(A + (size_t)(256 * g + 128) * N + 256 * g, N,
           Xi + (size_t)(256 * g) * (N + 1), N,
           U + g * 16384, 128, t >> 2, t & 3, 128, 1.0f, tid, sm);
  }
  gsync(bar, 3);
  if (b < 32) {
    int g = b >> 4, t = b & 15;
    gemm32(Xi + (size_t)(256 * g + 128) * (N + 1), N, U + g * 16384, 128,
           Xi + (size_t)(256 * g + 128) * N + 256 * g, N, t >> 2, t & 3, 128, h, tid, sm);
  }
  gsync(bar, 4);
  // PH5/PH6: level 256 -> 512
  if (b < 64)
    gemm32(A + (size_t)256 * N, N, Xi, N, U, 256, b >> 3, b & 7, 256, 1.0f, tid, sm);
  gsync(bar, 5);
  if (b < 64)
    gemm32(Xi + (size_t)256 * (N + 1), N, U, 256,
           Xi + (size_t)256 * N, N, b >> 3, b & 7, 256, h, tid, sm);
  gsync(bar, 6);
  // PH7: Bd
  if (b < 128) bd1_body(Xi, Bm, delta, Vt, b, tid, sm);
  gsync(bar, 7);
  // PH8..PH14: squaring + V doubling (Ad = 2*Xi - I read-transform at PH8)
  if (b < 64) sq64(Xi, B1, b >> 3, b & 7, tid, 1, sm);
  else if (b < 80) vstep_g(Xi, Vt, 1, 1, b - 64, tid, sm);
  gsync(bar, 8);
  if (b < 64) sq64(B1, B0, b >> 3, b & 7, tid, 0, sm);
  else if (b < 80) vstep_g(B1, Vt, 2, 0, b - 64, tid, sm);
  gsync(bar, 9);
  if (b < 64) sq64(B0, B1, b >> 3, b & 7, tid, 0, sm);
  else if (b < 80) vstep_g(B0, Vt, 4, 0, b - 64, tid, sm);
  gsync(bar, 10);
  if (b < 64) sq64(B1, B0, b >> 3, b & 7, tid, 0, sm);
  else if (b < 80) vstep_g(B1, Vt, 8, 0, b - 64, tid, sm);
  gsync(bar, 11);
  if (b < 64) sq64(B0, B1, b >> 3, b & 7, tid, 0, sm);
  else if (b < 80) vstep_g(B0, Vt, 16, 0, b - 64, tid, sm);
  gsync(bar, 12);
  if (b < 64) sq64(B1, B0, b >> 3, b & 7, tid, 0, sm);
  else if (b < 80) vstep_g(B1, Vt, 32, 0, b - 64, tid, sm);
  gsync(bar, 13);
  if (b < 64) sq64(B0, B1, b >> 3, b & 7, tid, 0, sm);
  else if (b < 96) vstep_g(B0, Vt, 64, 0, b - 64, tid, sm);
  gsync(bar, 14);
  // PH15..PH19: squaring + W doubling
  if (b < 64) sq64(B1, B0, b >> 3, b & 7, tid, 0, sm);
  else if (b < 80) wstep_g(B1, W, 1, b - 64, tid, sm);
  gsync(bar, 15);
  if (b < 64) sq64(B0, B1, b >> 3, b & 7, tid, 0, sm);
  else if (b < 80) wstep_g(B0, W, 2, b - 64, tid, sm);
  gsync(bar, 16);
  if (b < 64) sq64(B1, B0, b >> 3, b & 7, tid, 0, sm);
  else if (b < 80) wstep_g(B1, W, 4, b - 64, tid, sm);
  gsync(bar, 17);
  if (b < 64) sq64(B0, B1, b >> 3, b & 7, tid, 0, sm);
  else if (b < 80) wstep_g(B0, W, 8, b - 64, tid, sm);
  gsync(bar, 18);
  if (b < 64) sq64(B1, B0, b >> 3, b & 7, tid, 0, sm);
  else if (b < 80) wstep_g(B1, W, 16, b - 64, tid, sm);
  gsync(bar, 19);
  // PH20: last W doubling (P = B0 = Ad^4096)
  if (b < 16) wstep_g(B0, W, 32, b, tid, sm);
  gsync(bar, 20);
  // PH21: kvec = W * Vt
  if (b < 8)
    gemm32(W, N, Vt, 128, kvec, 128, b >> 2, b & 3, N, 1.0f, tid, sm);
  gsync(bar, 21);
  // PH22: Toeplitz B-frags from kvec
  if (b < 128) bfrag_unit(kvec, Btab, b * 256 + tid);
}

// Y = X * Toeplitz + D*X. Block p handles t-tile pair (p, 511-p): balanced.
__global__ __launch_bounds__(256) void k_convmm(const short8* __restrict__ Atab,
                                                const short8* __restrict__ Btab,
                                                const float* __restrict__ X,
                                                const float* __restrict__ Dp,
                                                float* __restrict__ Y) {
  __shared__ short8 bsh[32][64];
  int tid = threadIdx.x, lane = tid & 63, bt = tid >> 6;
  int p = blockIdx.x;
  int jL = p, jH = 511 - p;
  int nL = (jL + 2) >> 1, nH = (jH + 2) >> 1;
  f32x4 aL = {0.f, 0.f, 0.f, 0.f}, aH = {0.f, 0.f, 0.f, 0.f};
  const short8* Abase = Atab + (size_t)bt * 256 * 64 + lane;
  for (int u0 = 0; u0 < nH; u0 += 16) {
#pragma unroll
    for (int k = 0; k < 8; ++k) {
      int idx = tid + 256 * k;
      int f = idx >> 6, ln = idx & 63;
      int i = f & 15;
      int ut = u0 + i;
      if (f < 16) {
        if (ut < nH) bsh[i][ln] = Btab[(size_t)(jH - 2 * ut) * 64 + ln];
      } else {
        if (ut < nL) bsh[16 + i][ln] = Btab[(size_t)(jL - 2 * ut) * 64 + ln];
      }
    }
    __syncthreads();
    int m = (nH - u0 < 16) ? (nH - u0) : 16;
    for (int i = 0; i < m; ++i) {
      short8 a = Abase[(size_t)(u0 + i) * 64];
      aH = __builtin_amdgcn_mfma_f32_16x16x32_bf16(a, bsh[i][lane], aH, 0, 0, 0);
      if (u0 + i < nL)
        aL = __builtin_amdgcn_mfma_f32_16x16x32_bf16(a, bsh[16 + i][lane], aL, 0, 0, 0);
    }
    __syncthreads();
  }
  float D0 = Dp[0];
  int tt = lane & 15, rq = (lane >> 4) << 2;
#pragma unroll
  for (int r = 0; r < 4; ++r) {
    int bb = bt * 16 + rq + r;
    size_t oL = (size_t)bb * L + jL * 16 + tt;
    size_t oH = (size_t)bb * L + jH * 16 + tt;
    Y[oL] = aL[r] + D0 * X[oL];
    Y[oH] = aH[r] + D0 * X[oH];
  }
}

extern "C" void kernel_launch(void* const* d_in, const int* in_sizes, int n_in,
                              void* d_out, int out_size, void* d_ws, size_t ws_size,
                              hipStream_t stream) {
  const float* X  = (const float*)d_in[0];
  const float* A  = (const float*)d_in[1];
  const float* Bm = (const float*)d_in[2];
  const float* C  = (const float*)d_in[3];
  const float* D  = (const float*)d_in[4];
  const float* ld = (const float*)d_in[5];
  float* Y = (float*)d_out;

  float* ws = (float*)d_ws;
  float* kv = ws;                      // 8192
  float* Vt = ws + 8192;               // 512*128
  float* W  = ws + 73728;              // 64*512
  float* B0 = ws + 106496;             // 512*512
  float* B1 = ws + 368640;             // 512*512
  float* Xi = ws + 630784;             // 512*512
  unsigned* bar = (unsigned*)(ws + 892928);      // 64 uints
  unsigned int* Atab = (unsigned int*)(ws + 958464);   // 1MB
  unsigned int* Btab = (unsigned int*)(ws + 1220608);  // 512KB

  hipMemsetAsync(bar, 0, 64 * sizeof(unsigned), stream);
  k_chain<<<256, 256, 0, stream>>>(A, Bm, C, ld, X, Xi, B0, B1, Vt, W, kv,
                                   Atab, Btab, bar);
  k_convmm<<<256, 256, 0, stream>>>((const short8*)Atab, (const short8*)Btab, X, D, Y);
}

// Round 8
// 616.424 us; speedup vs baseline: 4.4367x; 1.6522x over previous
//
#include <hip/hip_runtime.h>

#define N 512
#define L 8192

#define LOG_MIN -6.907755278982137f
#define LOG_MAX -2.302585092994046f

typedef __attribute__((ext_vector_type(8))) short short8;
typedef __attribute__((ext_vector_type(4))) float f32x4;
typedef __attribute__((ext_vector_type(4))) unsigned int uint4v;

__device__ __forceinline__ float get_delta(const float* logd) {
  float ld = logd[0];
  ld = fminf(fmaxf(ld, LOG_MIN), LOG_MAX);
  return expf(ld);
}
__device__ __forceinline__ unsigned short f2bf(float x) {
  union { float f; unsigned int u; } c; c.f = x;
  unsigned int u = c.u;
  u += 0x7FFFu + ((u >> 16) & 1u);
  return (unsigned short)(u >> 16);
}
__device__ __forceinline__ unsigned int pack2(unsigned short a, unsigned short b) {
  return (unsigned int)a | ((unsigned int)b << 16);
}

// ---------------------------------------------------------------------------
// ws layout (floats):
//   0        kvec (8192)
//   8192     Vt   (512*128)
//   73728    W    (64*512)
//   106496   B0   (512*512)   U scratch / squaring ping
//   368640   B1   (512*512)   squaring pong
//   630784   Xi   (512*512)   A1^-1
//   892928   bar  (64 uint)   [0..20] chain, [32] convmm
//   958464   Atab (1MB bf16 A-frags)
//   1220608  Btab (512KB bf16 B-frags)
// ---------------------------------------------------------------------------

// Grid barrier: relaxed polling, one release fence before signal, one acquire
// fence after full count. Variable target (only alive blocks participate).
__device__ __forceinline__ void gsync(unsigned* bar, int p, unsigned tgt) {
  __syncthreads();
  if (threadIdx.x == 0) {
    __builtin_amdgcn_fence(__ATOMIC_RELEASE, "agent");
    __hip_atomic_fetch_add(&bar[p], 1u, __ATOMIC_RELAXED, __HIP_MEMORY_SCOPE_AGENT);
    while (__hip_atomic_load(&bar[p], __ATOMIC_RELAXED, __HIP_MEMORY_SCOPE_AGENT) < tgt)
      __builtin_amdgcn_s_sleep(8);
    __builtin_amdgcn_fence(__ATOMIC_ACQUIRE, "agent");
  }
  __syncthreads();
}
// signal-and-leave (for blocks exiting after this phase)
__device__ __forceinline__ void gsignal(unsigned* bar, int p) {
  __syncthreads();
  if (threadIdx.x == 0) {
    __builtin_amdgcn_fence(__ATOMIC_RELEASE, "agent");
    __hip_atomic_fetch_add(&bar[p], 1u, __ATOMIC_RELAXED, __HIP_MEMORY_SCOPE_AGENT);
  }
}

__device__ __forceinline__ void ld8(const float* p, float* v) {
  *(float4*)&v[0] = *(const float4*)p;
  *(float4*)&v[4] = *(const float4*)(p + 4);
}
__device__ __forceinline__ void tr8(float* v, int gr, int gc) {  // 2x - I
#pragma unroll
  for (int j = 0; j < 8; ++j) v[j] = 2.f * v[j] - ((gr == gc + j) ? 1.f : 0.f);
}

// --- phase bodies -----------------------------------------------------------

__device__ void diag64(const float* __restrict__ A, float h,
                       float* __restrict__ Xi, int blk, int tid, float* sm) {
  float* Ash = sm;          // [64][65]
  float* xs  = sm + 4160;   // [64][65]
  float* dinv = sm + 8320;  // [64]
  int i0 = blk * 64;
  int r = tid >> 2, c0 = (tid & 3) * 16;
#pragma unroll
  for (int q = 0; q < 16; q += 4) {
    float4 v = *(const float4*)(A + (size_t)(i0 + r) * N + i0 + c0 + q);
    Ash[r * 65 + c0 + q] = v.x; Ash[r * 65 + c0 + q + 1] = v.y;
    Ash[r * 65 + c0 + q + 2] = v.z; Ash[r * 65 + c0 + q + 3] = v.w;
  }
  for (int i = tid; i < 4160; i += 256) xs[i] = 0.f;
  __syncthreads();
  if (tid < 64) dinv[tid] = 1.f / (1.f - h * Ash[tid * 65 + tid]);
  __syncthreads();
  int t = tid >> 2, sub = tid & 3;
  for (int rr = 0; rr < 64; ++rr) {
    if (t <= rr) {
      float s = 0.f;
      for (int k = t + sub; k < rr; k += 4) s += Ash[rr * 65 + k] * xs[k * 65 + t];
      s += __shfl_xor(s, 1, 64);
      s += __shfl_xor(s, 2, 64);
      if (sub == 0)
        xs[rr * 65 + t] = (((rr == t) ? 1.f : 0.f) + h * s) * dinv[rr];
    }
  }
  __syncthreads();
#pragma unroll
  for (int q = 0; q < 16; q += 4) {
    float4 v = {xs[r * 65 + c0 + q], xs[r * 65 + c0 + q + 1],
                xs[r * 65 + c0 + q + 2], xs[r * 65 + c0 + q + 3]};
    *(float4*)(Xi + (size_t)(i0 + r) * N + i0 + c0 + q) = v;
  }
}

// Pipelined 32x32-tile GEMM: C_ tile (bi,bj) = alpha * A_ * B_ over K.
__device__ void gemm32(const float* __restrict__ A_, int lda,
                       const float* __restrict__ B_, int ldb,
                       float* __restrict__ C_, int ldc,
                       int bi, int bj, int K, float alpha, int tid, float* sm) {
  float* As = sm;          // [32][33]
  float* Bs = sm + 1056;   // [32][33]
  int tx = tid & 31, ty = tid >> 5;
  int lr = tid >> 3, lc = (tid & 7) * 4;
  const float* ap = A_ + (size_t)(bi * 32 + lr) * lda + lc;
  const float* bp = B_ + (size_t)lr * ldb + bj * 32 + lc;
  float4 a_c = *(const float4*)ap;
  float4 b_c = *(const float4*)bp;
  float acc[4] = {0.f, 0.f, 0.f, 0.f};
  for (int kb = 0; kb < K; kb += 32) {
    float4 a_n, b_n;
    if (kb + 32 < K) {                       // prefetch next K-tile
      a_n = *(const float4*)(ap + kb + 32);
      b_n = *(const float4*)(bp + (size_t)(kb + 32) * ldb);
    }
    As[lr * 33 + lc] = a_c.x; As[lr * 33 + lc + 1] = a_c.y;
    As[lr * 33 + lc + 2] = a_c.z; As[lr * 33 + lc + 3] = a_c.w;
    Bs[lr * 33 + lc] = b_c.x; Bs[lr * 33 + lc + 1] = b_c.y;
    Bs[lr * 33 + lc + 2] = b_c.z; Bs[lr * 33 + lc + 3] = b_c.w;
    __syncthreads();
#pragma unroll
    for (int kk = 0; kk < 32; ++kk) {
      float bv = Bs[kk * 33 + tx];
#pragma unroll
      for (int m = 0; m < 4; ++m) acc[m] += As[(ty + 8 * m) * 33 + kk] * bv;
    }
    __syncthreads();
    a_c = a_n; b_c = b_n;
  }
#pragma unroll
  for (int m = 0; m < 4; ++m)
    C_[(size_t)(bi * 32 + ty + 8 * m) * ldc + bj * 32 + tx] = alpha * acc[m];
}

// Pipelined 64x64-tile lower-tri squaring: Q = P*P (first: P := 2P - I on read).
__device__ void sq64(const float* __restrict__ P, float* __restrict__ Q,
                     int bi, int bj, int tid, int first, float* sm) {
  if (bi < bj) {
    int r = tid >> 2, cq = (tid & 3) * 16;
    float4 z = {0.f, 0.f, 0.f, 0.f};
#pragma unroll
    for (int j = 0; j < 4; ++j)
      *(float4*)(Q + (size_t)(bi * 64 + r) * N + bj * 64 + cq + 4 * j) = z;
    return;
  }
  float* Ast = sm;            // [32][68]
  float* Bs = sm + 2176;      // [32][64]
  int tx = tid & 15, ty = tid >> 4;
  float acc[4][4];
#pragma unroll
  for (int i = 0; i < 4; ++i)
#pragma unroll
    for (int j = 0; j < 4; ++j) acc[i][j] = 0.f;
  int ar = tid >> 2, aq = tid & 3;
  int bk = tid >> 3, bc = (tid & 7) * 8;
  const float* arow = P + (size_t)(bi * 64 + ar) * N + aq * 8;
  const float* brow = P + (size_t)bk * N + bj * 64 + bc;
  int kb0 = bj * 64, kbend = (bi + 1) * 64;
  float av[8], bv[8];
  ld8(arow + kb0, av);
  ld8(brow + (size_t)kb0 * N, bv);
  if (first) { tr8(av, bi * 64 + ar, kb0 + aq * 8); tr8(bv, kb0 + bk, bj * 64 + bc); }
  for (int kb = kb0; kb < kbend; kb += 32) {
    float avn[8], bvn[8];
    if (kb + 32 < kbend) {                   // prefetch next K-tile
      ld8(arow + kb + 32, avn);
      ld8(brow + (size_t)(kb + 32) * N, bvn);
      if (first) { tr8(avn, bi * 64 + ar, kb + 32 + aq * 8); tr8(bvn, kb + 32 + bk, bj * 64 + bc); }
    }
#pragma unroll
    for (int j = 0; j < 8; ++j) Ast[(aq * 8 + j) * 68 + ar] = av[j];
    *(float4*)&Bs[bk * 64 + bc] = *(float4*)&bv[0];
    *(float4*)&Bs[bk * 64 + bc + 4] = *(float4*)&bv[4];
    __syncthreads();
#pragma unroll 8
    for (int k = 0; k < 32; ++k) {
      float4 a = *(const float4*)&Ast[k * 68 + 4 * ty];
      float4 bb = *(const float4*)&Bs[k * 64 + 4 * tx];
      float ai[4] = {a.x, a.y, a.z, a.w};
      float bj4[4] = {bb.x, bb.y, bb.z, bb.w};
#pragma unroll
      for (int i = 0; i < 4; ++i)
#pragma unroll
        for (int j = 0; j < 4; ++j) acc[i][j] = fmaf(ai[i], bj4[j], acc[i][j]);
    }
    __syncthreads();
#pragma unroll
    for (int j = 0; j < 8; ++j) { av[j] = avn[j]; bv[j] = bvn[j]; }
  }
#pragma unroll
  for (int i = 0; i < 4; ++i) {
    float4 v = {acc[i][0], acc[i][1], acc[i][2], acc[i][3]};
    *(float4*)(Q + (size_t)(bi * 64 + 4 * ty + i) * N + bj * 64 + 4 * tx) = v;
  }
}

// Pipelined: Vt[:, base+c] = (first ? 2P-I : P) * Vt[:, c], c < base.
__device__ void vstep_g(const float* __restrict__ P, float* __restrict__ Vt,
                        int base, int first, int idx, int tid, float* sm) {
  int bi = idx & 15, cj = idx >> 4;
  float* As = sm;
  float* Bs = sm + 1056;
  int tx = tid & 31, ty = tid >> 5;
  int lr = tid >> 3, lc = (tid & 7) * 4;
  int arow = bi * 32 + lr;
  const float* ap = P + (size_t)arow * N + lc;
  const float* bp = Vt + (size_t)lr * 128 + cj * 32 + lc;
  int kmax = (bi + 1) * 32;
  float4 a_c = *(const float4*)ap;
  float4 b_c = *(const float4*)bp;
  float acc[4] = {0.f, 0.f, 0.f, 0.f};
  for (int kb = 0; kb < kmax; kb += 32) {
    float4 a_n, b_n;
    if (kb + 32 < kmax) {
      a_n = *(const float4*)(ap + kb + 32);
      b_n = *(const float4*)(bp + (size_t)(kb + 32) * 128);
    }
    float a4[4] = {a_c.x, a_c.y, a_c.z, a_c.w};
    if (first) {
#pragma unroll
      for (int j = 0; j < 4; ++j)
        a4[j] = 2.f * a4[j] - ((arow == kb + lc + j) ? 1.f : 0.f);
    }
    As[lr * 33 + lc] = a4[0]; As[lr * 33 + lc + 1] = a4[1];
    As[lr * 33 + lc + 2] = a4[2]; As[lr * 33 + lc + 3] = a4[3];
    Bs[lr * 33 + lc] = b_c.x; Bs[lr * 33 + lc + 1] = b_c.y;
    Bs[lr * 33 + lc + 2] = b_c.z; Bs[lr * 33 + lc + 3] = b_c.w;
    __syncthreads();
#pragma unroll
    for (int kk = 0; kk < 32; ++kk) {
      float bv = Bs[kk * 33 + tx];
#pragma unroll
      for (int m = 0; m < 4; ++m) acc[m] += As[(ty + 8 * m) * 33 + kk] * bv;
    }
    __syncthreads();
    a_c = a_n; b_c = b_n;
  }
  int c = cj * 32 + tx;
  if (c < base) {
#pragma unroll
    for (int m = 0; m < 4; ++m)
      Vt[(size_t)(bi * 32 + ty + 8 * m) * 128 + base + c] = acc[m];
  }
}

// Pipelined: W[base+q][:] = W[q][:] * P, q < base. Column tile cj.
__device__ void wstep_g(const float* __restrict__ P, float* __restrict__ W,
                        int base, int cj, int tid, float* sm) {
  float* As = sm;
  float* Bs = sm + 1056;
  int tx = tid & 31, ty = tid >> 5;
  int lr = tid >> 3, lc = (tid & 7) * 4;
  const float* ap = W + (size_t)lr * N + lc;
  const float* bp = P + (size_t)lr * N + cj * 32 + lc;
  float4 a_c = *(const float4*)ap;
  float4 b_c = *(const float4*)bp;
  float acc[4] = {0.f, 0.f, 0.f, 0.f};
  for (int kb = 0; kb < N; kb += 32) {
    float4 a_n, b_n;
    if (kb + 32 < N) {
      a_n = *(const float4*)(ap + kb + 32);
      b_n = *(const float4*)(bp + (size_t)(kb + 32) * N);
    }
    As[lr * 33 + lc] = a_c.x; As[lr * 33 + lc + 1] = a_c.y;
    As[lr * 33 + lc + 2] = a_c.z; As[lr * 33 + lc + 3] = a_c.w;
    Bs[lr * 33 + lc] = b_c.x; Bs[lr * 33 + lc + 1] = b_c.y;
    Bs[lr * 33 + lc + 2] = b_c.z; Bs[lr * 33 + lc + 3] = b_c.w;
    __syncthreads();
#pragma unroll
    for (int kk = 0; kk < 32; ++kk) {
      float bv = Bs[kk * 33 + tx];
#pragma unroll
      for (int m = 0; m < 4; ++m) acc[m] += As[(ty + 8 * m) * 33 + kk] * bv;
    }
    __syncthreads();
    a_c = a_n; b_c = b_n;
  }
#pragma unroll
  for (int m = 0; m < 4; ++m) {
    int q = ty + 8 * m;
    if (q < base) W[(size_t)(base + q) * N + cj * 32 + tx] = acc[m];
  }
}

// Vt[:,0] = delta * Xi * Bm: 64 blocks x 8 rows (2 per wave).
__device__ void bd1_body(const float* __restrict__ Xi, const float* __restrict__ Bm,
                         float delta, float* __restrict__ Vt, int blk, int tid,
                         float* sm) {
  float* bs = sm;
  if (tid < 128) ((float4*)bs)[tid] = ((const float4*)Bm)[tid];
  __syncthreads();
  int w = tid >> 6, lane = tid & 63;
#pragma unroll
  for (int pass = 0; pass < 2; ++pass) {
    int row = blk * 8 + w * 2 + pass;
    const float* Xr = Xi + (size_t)row * N + lane * 8;
    float4 a0 = *(const float4*)Xr;
    float4 a1 = *(const float4*)(Xr + 4);
    const float* bp = bs + lane * 8;
    float acc = a0.x * bp[0] + a0.y * bp[1] + a0.z * bp[2] + a0.w * bp[3]
              + a1.x * bp[4] + a1.y * bp[5] + a1.z * bp[6] + a1.w * bp[7];
    acc += __shfl_xor(acc, 1, 64);
    acc += __shfl_xor(acc, 2, 64);
    acc += __shfl_xor(acc, 4, 64);
    acc += __shfl_xor(acc, 8, 64);
    acc += __shfl_xor(acc, 16, 64);
    acc += __shfl_xor(acc, 32, 64);
    if (lane == 0) Vt[(size_t)row * 128] = delta * acc;
  }
}

__device__ __forceinline__ void afrag_unit(const float* __restrict__ X,
                                           unsigned int* __restrict__ Atab, int u) {
  int lane = u & 63;
  int f = u >> 6;
  int bt = f >> 8, ut = f & 255;
  int row = bt * 16 + (lane & 15);
  int u0 = ut * 32 + ((lane >> 4) << 3);
  const float* xp = X + (size_t)row * L + u0;
  unsigned short v[8];
#pragma unroll
  for (int e = 0; e < 8; ++e) v[e] = f2bf(xp[e]);
  uint4v o;
  o.x = pack2(v[0], v[1]); o.y = pack2(v[2], v[3]);
  o.z = pack2(v[4], v[5]); o.w = pack2(v[6], v[7]);
  ((uint4v*)Atab)[(size_t)f * 64 + lane] = o;
}

__device__ __forceinline__ void bfrag_unit(const float* __restrict__ kvec,
                                           unsigned int* __restrict__ Btab, int u) {
  int lane = u & 63;
  int si = u >> 6;
  int base = si * 16 + (lane & 15) - ((lane >> 4) << 3);
  unsigned short v[8];
#pragma unroll
  for (int e = 0; e < 8; ++e) {
    int idx = base - e;
    float x = (idx >= 0) ? kvec[idx] : 0.0f;
    v[e] = f2bf(x);
  }
  uint4v o;
  o.x = pack2(v[0], v[1]); o.y = pack2(v[2], v[3]);
  o.z = pack2(v[4], v[5]); o.w = pack2(v[6], v[7]);
  ((uint4v*)Btab)[(size_t)si * 64 + lane] = o;
}

// --- fused serial chain: 96 blocks, 21 barriers ----------------------------
__global__ __launch_bounds__(256, 2) void k_chain(
    const float* __restrict__ A, const float* __restrict__ Bm,
    const float* __restrict__ C, const float* __restrict__ logd,
    float* __restrict__ Xi, float* __restrict__ B0, float* __restrict__ B1,
    float* __restrict__ Vt, float* __restrict__ W, float* __restrict__ kvec,
    unsigned* bar) {
  __shared__ float sm[8704];
  int b = blockIdx.x, tid = threadIdx.x;
  float delta = get_delta(logd);
  float h = 0.5f * delta;
  float* U = B0;

  // PH0: diag inverses + zero strict-upper 64-tiles + W[0]=C
  if (b < 8) {
    diag64(A, h, Xi, b, tid, sm);
  } else if (b < 36) {
    int idx = b - 8, bi = 0, bj = 0, cnt = 0;
    for (int i = 0; i < 8; ++i)
      for (int j = i + 1; j < 8; ++j) { if (cnt == idx) { bi = i; bj = j; } ++cnt; }
    int r = tid >> 2, c0 = (tid & 3) * 16;
    float4 z = {0.f, 0.f, 0.f, 0.f};
#pragma unroll
    for (int q = 0; q < 16; q += 4)
      *(float4*)(Xi + (size_t)(bi * 64 + r) * N + bj * 64 + c0 + q) = z;
  } else if (b == 36) {
    for (int i = tid; i < N; i += 256) W[i] = C[i];
  }
  gsync(bar, 0, 96);
  // PH1/PH2: level 64 -> 128
  if (b < 16) {
    int g = b >> 2, t = b & 3;
    gemm32(A + (size_t)(128 * g + 64) * N + 128 * g, N,
           Xi + (size_t)(128 * g) * (N + 1), N,
           U + g * 4096, 64, t >> 1, t & 1, 64, 1.0f, tid, sm);
  }
  gsync(bar, 1, 96);
  if (b < 16) {
    int g = b >> 2, t = b & 3;
    gemm32(Xi + (size_t)(128 * g + 64) * (N + 1), N, U + g * 4096, 64,
           Xi + (size_t)(128 * g + 64) * N + 128 * g, N, t >> 1, t & 1, 64, h, tid, sm);
  }
  gsync(bar, 2, 96);
  // PH3/PH4: level 128 -> 256
  if (b < 32) {
    int g = b >> 4, t = b & 15;
    gemm32(A + (size_t)(256 * g + 128) * N + 256 * g, N,
           Xi + (size_t)(256 * g) * (N + 1), N,
           U + g * 16384, 128, t >> 2, t & 3, 128, 1.0f, tid, sm);
  }
  gsync(bar, 3, 96);
  if (b < 32) {
    int g = b >> 4, t = b & 15;
    gemm32(Xi + (size_t)(256 * g + 128) * (N + 1), N, U + g * 16384, 128,
           Xi + (size_t)(256 * g + 128) * N + 256 * g, N, t >> 2, t & 3, 128, h, tid, sm);
  }
  gsync(bar, 4, 96);
  // PH5/PH6: level 256 -> 512
  if (b < 64)
    gemm32(A + (size_t)256 * N, N, Xi, N, U, 256, b >> 3, b & 7, 256, 1.0f, tid, sm);
  gsync(bar, 5, 96);
  if (b < 64)
    gemm32(Xi + (size_t)256 * (N + 1), N, U, 256,
           Xi + (size_t)256 * N, N, b >> 3, b & 7, 256, h, tid, sm);
  gsync(bar, 6, 96);
  // PH7: Bd
  if (b < 64) bd1_body(Xi, Bm, delta, Vt, b, tid, sm);
  gsync(bar, 7, 96);
  // PH8..PH14: squaring + V doubling (Ad = 2*Xi - I read-transform at PH8)
  if (b < 64) sq64(Xi, B1, b >> 3, b & 7, tid, 1, sm);
  else if (b < 80) vstep_g(Xi, Vt, 1, 1, b - 64, tid, sm);
  gsync(bar, 8, 96);
  if (b < 64) sq64(B1, B0, b >> 3, b & 7, tid, 0, sm);
  else if (b < 80) vstep_g(B1, Vt, 2, 0, b - 64, tid, sm);
  gsync(bar, 9, 96);
  if (b < 64) sq64(B0, B1, b >> 3, b & 7, tid, 0, sm);
  else if (b < 80) vstep_g(B0, Vt, 4, 0, b - 64, tid, sm);
  gsync(bar, 10, 96);
  if (b < 64) sq64(B1, B0, b >> 3, b & 7, tid, 0, sm);
  else if (b < 80) vstep_g(B1, Vt, 8, 0, b - 64, tid, sm);
  gsync(bar, 11, 96);
  if (b < 64) sq64(B0, B1, b >> 3, b & 7, tid, 0, sm);
  else if (b < 80) vstep_g(B0, Vt, 16, 0, b - 64, tid, sm);
  gsync(bar, 12, 96);
  if (b < 64) sq64(B1, B0, b >> 3, b & 7, tid, 0, sm);
  else if (b < 80) vstep_g(B1, Vt, 32, 0, b - 64, tid, sm);
  gsync(bar, 13, 96);
  if (b < 64) sq64(B0, B1, b >> 3, b & 7, tid, 0, sm);
  else vstep_g(B0, Vt, 64, 0, b - 64, tid, sm);   // b = 64..95
  if (b >= 80) { gsignal(bar, 14); return; }       // blocks 80-95 retire
  gsync(bar, 14, 96);
  // PH15..PH19: squaring + W doubling
  if (b < 64) sq64(B1, B0, b >> 3, b & 7, tid, 0, sm);
  else wstep_g(B1, W, 1, b - 64, tid, sm);
  gsync(bar, 15, 80);
  if (b < 64) sq64(B0, B1, b >> 3, b & 7, tid, 0, sm);
  else wstep_g(B0, W, 2, b - 64, tid, sm);
  gsync(bar, 16, 80);
  if (b < 64) sq64(B1, B0, b >> 3, b & 7, tid, 0, sm);
  else wstep_g(B1, W, 4, b - 64, tid, sm);
  gsync(bar, 17, 80);
  if (b < 64) sq64(B0, B1, b >> 3, b & 7, tid, 0, sm);
  else wstep_g(B0, W, 8, b - 64, tid, sm);
  gsync(bar, 18, 80);
  if (b < 64) sq64(B1, B0, b >> 3, b & 7, tid, 0, sm);
  else wstep_g(B1, W, 16, b - 64, tid, sm);
  if (b >= 64) { gsignal(bar, 19); return; }       // blocks 64-79 retire
  gsync(bar, 19, 80);
  // PH20: last W doubling (P = B0 = Ad^4096)
  if (b < 16) wstep_g(B0, W, 32, b, tid, sm);
  gsync(bar, 20, 64);
  // PH21: kvec = W * Vt  (kernel end = release)
  if (b < 8)
    gemm32(W, N, Vt, 128, kvec, 128, b >> 2, b & 3, N, 1.0f, tid, sm);
}

// Prologue: fill Atab/Btab (all 256 blocks), grid-sync, then balanced conv.
__global__ __launch_bounds__(256, 2) void k_convmm(unsigned int* __restrict__ AtabW,
                                                   unsigned int* __restrict__ BtabW,
                                                   const float* __restrict__ kvec,
                                                   const float* __restrict__ X,
                                                   const float* __restrict__ Dp,
                                                   float* __restrict__ Y,
                                                   unsigned* bar) {
  __shared__ short8 bsh[32][64];
  int tid = threadIdx.x, lane = tid & 63, bt = tid >> 6;
  int p = blockIdx.x;
  afrag_unit(X, AtabW, p * 256 + tid);
  if (p < 128) bfrag_unit(kvec, BtabW, p * 256 + tid);
  gsync(bar, 0, 256);
  const short8* Atab = (const short8*)AtabW;
  const short8* Btab = (const short8*)BtabW;
  int jL = p, jH = 511 - p;
  int nL = (jL + 2) >> 1, nH = (jH + 2) >> 1;
  f32x4 aL = {0.f, 0.f, 0.f, 0.f}, aH = {0.f, 0.f, 0.f, 0.f};
  const short8* Abase = Atab + (size_t)bt * 256 * 64 + lane;
  for (int u0 = 0; u0 < nH; u0 += 16) {
#pragma unroll
    for (int k = 0; k < 8; ++k) {
      int idx = tid + 256 * k;
      int f = idx >> 6, ln = idx & 63;
      int i = f & 15;
      int ut = u0 + i;
      if (f < 16) {
        if (ut < nH) bsh[i][ln] = Btab[(size_t)(jH - 2 * ut) * 64 + ln];
      } else {
        if (ut < nL) bsh[16 + i][ln] = Btab[(size_t)(jL - 2 * ut) * 64 + ln];
      }
    }
    __syncthreads();
    int m = (nH - u0 < 16) ? (nH - u0) : 16;
    for (int i = 0; i < m; ++i) {
      short8 a = Abase[(size_t)(u0 + i) * 64];
      aH = __builtin_amdgcn_mfma_f32_16x16x32_bf16(a, bsh[i][lane], aH, 0, 0, 0);
      if (u0 + i < nL)
        aL = __builtin_amdgcn_mfma_f32_16x16x32_bf16(a, bsh[16 + i][lane], aL, 0, 0, 0);
    }
    __syncthreads();
  }
  float D0 = Dp[0];
  int tt = lane & 15, rq = (lane >> 4) << 2;
#pragma unroll
  for (int r = 0; r < 4; ++r) {
    int bb = bt * 16 + rq + r;
    size_t oL = (size_t)bb * L + jL * 16 + tt;
    size_t oH = (size_t)bb * L + jH * 16 + tt;
    Y[oL] = aL[r] + D0 * X[oL];
    Y[oH] = aH[r] + D0 * X[oH];
  }
}

extern "C" void kernel_launch(void* const* d_in, const int* in_sizes, int n_in,
                              void* d_out, int out_size, void* d_ws, size_t ws_size,
                              hipStream_t stream) {
  const float* X  = (const float*)d_in[0];
  const float* A  = (const float*)d_in[1];
  const float* Bm = (const float*)d_in[2];
  const float* C  = (const float*)d_in[3];
  const float* D  = (const float*)d_in[4];
  const float* ld = (const float*)d_in[5];
  float* Y = (float*)d_out;

  float* ws = (float*)d_ws;
  float* kv = ws;                      // 8192
  float* Vt = ws + 8192;               // 512*128
  float* W  = ws + 73728;              // 64*512
  float* B0 = ws + 106496;             // 512*512
  float* B1 = ws + 368640;             // 512*512
  float* Xi = ws + 630784;             // 512*512
  unsigned* bar = (unsigned*)(ws + 892928);            // [0..20] chain, [32] conv
  unsigned int* Atab = (unsigned int*)(ws + 958464);   // 1MB
  unsigned int* Btab = (unsigned int*)(ws + 1220608);  // 512KB

  hipMemsetAsync(bar, 0, 64 * sizeof(unsigned), stream);
  k_chain<<<96, 256, 0, stream>>>(A, Bm, C, ld, Xi, B0, B1, Vt, W, kv, bar);
  k_convmm<<<256, 256, 0, stream>>>(Atab, Btab, kv, X, D, Y, bar + 32);
}

// Round 9
// 569.113 us; speedup vs baseline: 4.8055x; 1.0831x over previous
//
#include <hip/hip_runtime.h>

#define N 512
#define L 8192

#define LOG_MIN -6.907755278982137f
#define LOG_MAX -2.302585092994046f

typedef __attribute__((ext_vector_type(8))) short short8;
typedef __attribute__((ext_vector_type(4))) float f32x4;

__device__ __forceinline__ float get_delta(const float* logd) {
  float ld = logd[0];
  ld = fminf(fmaxf(ld, LOG_MIN), LOG_MAX);
  return expf(ld);
}
__device__ __forceinline__ unsigned short f2bf(float x) {
  union { float f; unsigned int u; } c; c.f = x;
  unsigned int u = c.u;
  u += 0x7FFFu + ((u >> 16) & 1u);
  return (unsigned short)(u >> 16);
}
__device__ __forceinline__ unsigned int pack2(unsigned short a, unsigned short b) {
  return (unsigned int)a | ((unsigned int)b << 16);
}

// Agent-visible write-through stores (sc1): cross-XCD safe without fences,
// given the line-granular write-once discipline documented per buffer below.
__device__ __forceinline__ void ast(float* p, float v) {
  __hip_atomic_store(p, v, __ATOMIC_RELAXED, __HIP_MEMORY_SCOPE_AGENT);
}
__device__ __forceinline__ void ast4(float* p, float4 v) {
  ast(p, v.x); ast(p + 1, v.y); ast(p + 2, v.z); ast(p + 3, v.w);
}
__device__ __forceinline__ void astu(unsigned* p, unsigned v) {
  __hip_atomic_store(p, v, __ATOMIC_RELAXED, __HIP_MEMORY_SCOPE_AGENT);
}

// Fence-free grid barrier: all waves drain stores (vmcnt0 = release ordering
// for the already-write-through data), then relaxed add + relaxed poll.
__device__ __forceinline__ void gsync(unsigned* bar, int p, unsigned tgt) {
  asm volatile("s_waitcnt vmcnt(0)" ::: "memory");
  __syncthreads();
  if (threadIdx.x == 0) {
    __hip_atomic_fetch_add(&bar[p], 1u, __ATOMIC_RELAXED, __HIP_MEMORY_SCOPE_AGENT);
    while (__hip_atomic_load(&bar[p], __ATOMIC_RELAXED, __HIP_MEMORY_SCOPE_AGENT) < tgt)
      __builtin_amdgcn_s_sleep(2);
  }
  __syncthreads();
}

// ---------------------------------------------------------------------------
// ws layout (floats). Every buffer is written exactly once per address during
// k_chain, and never read before its write (cache-line granular).
//   0        bar   (64 u32)
//   64       kvec  (8192)       [64][128], written PH21
//   8256     Vtr   (128*512)    Vtr[r][n] = (Ad^r Bd)[n]; row r written whole
//   73792    W     (64*512)     row q written whole
//   106560   Xi    (512*512)    A1^-1 (tile-wise write-once)
//   368704   U1    (4*64*64)
//   385088   U2    (2*128*128)
//   417856   U3    (256*256)
//   483392   PB[12] 12*512*512  Ad^2,4,...,4096 (lower+diag tiles only)
//   Atab aliases Xi, Btab aliases PB[0] (used only by the conv dispatch).
// ---------------------------------------------------------------------------

__device__ void diag64(const float* __restrict__ A, float h,
                       float* __restrict__ Xi, int blk, int tid, float* sm) {
  float* Ash = sm;          // [64][65]
  float* xs  = sm + 4160;   // [64][65]
  float* dinv = sm + 8320;  // [64]
  int i0 = blk * 64;
  int r = tid >> 2, c0 = (tid & 3) * 16;
#pragma unroll
  for (int q = 0; q < 16; q += 4) {
    float4 v = *(const float4*)(A + (size_t)(i0 + r) * N + i0 + c0 + q);
    Ash[r * 65 + c0 + q] = v.x; Ash[r * 65 + c0 + q + 1] = v.y;
    Ash[r * 65 + c0 + q + 2] = v.z; Ash[r * 65 + c0 + q + 3] = v.w;
  }
  for (int i = tid; i < 4160; i += 256) xs[i] = 0.f;
  __syncthreads();
  if (tid < 64) dinv[tid] = 1.f / (1.f - h * Ash[tid * 65 + tid]);
  __syncthreads();
  int t = tid >> 2, sub = tid & 3;
  for (int rr = 0; rr < 64; ++rr) {
    if (t <= rr) {
      float s = 0.f;
      for (int k = t + sub; k < rr; k += 4) s += Ash[rr * 65 + k] * xs[k * 65 + t];
      s += __shfl_xor(s, 1, 64);
      s += __shfl_xor(s, 2, 64);
      if (sub == 0)
        xs[rr * 65 + t] = (((rr == t) ? 1.f : 0.f) + h * s) * dinv[rr];
    }
  }
  __syncthreads();
#pragma unroll
  for (int q = 0; q < 16; q += 4) {
    float4 v = {xs[r * 65 + c0 + q], xs[r * 65 + c0 + q + 1],
                xs[r * 65 + c0 + q + 2], xs[r * 65 + c0 + q + 3]};
    ast4(Xi + (size_t)(i0 + r) * N + i0 + c0 + q, v);
  }
}

// Pipelined 32x32-tile GEMM: C_ tile (bi,bj) = alpha * A_ * B_ over K.
__device__ void gemm32(const float* __restrict__ A_, int lda,
                       const float* __restrict__ B_, int ldb,
                       float* __restrict__ C_, int ldc,
                       int bi, int bj, int K, float alpha, int tid, float* sm) {
  float* As = sm;          // [32][33]
  float* Bs = sm + 1056;   // [32][33]
  int tx = tid & 31, ty = tid >> 5;
  int lr = tid >> 3, lc = (tid & 7) * 4;
  const float* ap = A_ + (size_t)(bi * 32 + lr) * lda + lc;
  const float* bp = B_ + (size_t)lr * ldb + bj * 32 + lc;
  float4 a_c = *(const float4*)ap;
  float4 b_c = *(const float4*)bp;
  float acc[4] = {0.f, 0.f, 0.f, 0.f};
  for (int kb = 0; kb < K; kb += 32) {
    float4 a_n, b_n;
    if (kb + 32 < K) {
      a_n = *(const float4*)(ap + kb + 32);
      b_n = *(const float4*)(bp + (size_t)(kb + 32) * ldb);
    }
    As[lr * 33 + lc] = a_c.x; As[lr * 33 + lc + 1] = a_c.y;
    As[lr * 33 + lc + 2] = a_c.z; As[lr * 33 + lc + 3] = a_c.w;
    Bs[lr * 33 + lc] = b_c.x; Bs[lr * 33 + lc + 1] = b_c.y;
    Bs[lr * 33 + lc + 2] = b_c.z; Bs[lr * 33 + lc + 3] = b_c.w;
    __syncthreads();
#pragma unroll
    for (int kk = 0; kk < 32; ++kk) {
      float bv = Bs[kk * 33 + tx];
#pragma unroll
      for (int m = 0; m < 4; ++m) acc[m] += As[(ty + 8 * m) * 33 + kk] * bv;
    }
    __syncthreads();
    a_c = a_n; b_c = b_n;
  }
#pragma unroll
  for (int m = 0; m < 4; ++m)
    ast(&C_[(size_t)(bi * 32 + ty + 8 * m) * ldc + bj * 32 + tx], alpha * acc[m]);
}

// 32x32-tile lower-tri squaring: Q = P*P (first: P := 2P - I on read).
// Only lower+diag tiles (bj<=bi) are computed; upper tiles never written/read.
__device__ void sq32(const float* __restrict__ P, float* __restrict__ Q,
                     int bi, int bj, int first, int tid, float* sm) {
  float* As = sm;          // [32][33]  A[n][k]
  float* Bs = sm + 1056;   // [32][33]  B[k][c]
  int tx = tid & 31, ty = tid >> 5;
  int lr = tid >> 3, lc = (tid & 7) * 4;
  int kb0 = bj * 32, kbend = (bi + 1) * 32;
  int arow = bi * 32 + lr;
  const float* ap = P + (size_t)arow * N + lc;
  const float* bp = P + bj * 32 + lc;
  float4 a_c = *(const float4*)(ap + kb0);
  float4 b_c = *(const float4*)(bp + (size_t)(kb0 + lr) * N);
  float acc[4] = {0.f, 0.f, 0.f, 0.f};
  for (int kb = kb0; kb < kbend; kb += 32) {
    float4 a_n, b_n;
    if (kb + 32 < kbend) {
      a_n = *(const float4*)(ap + kb + 32);
      b_n = *(const float4*)(bp + (size_t)(kb + 32 + lr) * N);
    }
    float a4[4] = {a_c.x, a_c.y, a_c.z, a_c.w};
    float b4[4] = {b_c.x, b_c.y, b_c.z, b_c.w};
    if (first) {
#pragma unroll
      for (int j = 0; j < 4; ++j) {
        a4[j] = 2.f * a4[j] - ((arow == kb + lc + j) ? 1.f : 0.f);
        b4[j] = 2.f * b4[j] - ((kb + lr == bj * 32 + lc + j) ? 1.f : 0.f);
      }
    }
    As[lr * 33 + lc] = a4[0]; As[lr * 33 + lc + 1] = a4[1];
    As[lr * 33 + lc + 2] = a4[2]; As[lr * 33 + lc + 3] = a4[3];
    Bs[lr * 33 + lc] = b4[0]; Bs[lr * 33 + lc + 1] = b4[1];
    Bs[lr * 33 + lc + 2] = b4[2]; Bs[lr * 33 + lc + 3] = b4[3];
    __syncthreads();
#pragma unroll
    for (int kk = 0; kk < 32; ++kk) {
      float bv = Bs[kk * 33 + tx];
#pragma unroll
      for (int m = 0; m < 4; ++m) acc[m] += As[(ty + 8 * m) * 33 + kk] * bv;
    }
    __syncthreads();
    a_c = a_n; b_c = b_n;
  }
#pragma unroll
  for (int m = 0; m < 4; ++m)
    ast(&Q[(size_t)(bi * 32 + ty + 8 * m) * N + bj * 32 + tx], acc[m]);
}

// Vtr[base+c][n] = sum_k P[n][k] * Vtr[c][k]  (first: P := 2P - I on read).
// Loads of Vtr rows >= base are suppressed (lines must not be cached early).
__device__ void vstep_g(const float* __restrict__ P, float* __restrict__ Vtr,
                        int base, int first, int idx, int tid, float* sm) {
  int bi = idx & 15, cj = idx >> 4;
  float* As = sm;          // [32][33]  A[n][k]
  float* Bs = sm + 1056;   // [32][33]  B[c][k]
  int tx = tid & 31, ty = tid >> 5;
  int lr = tid >> 3, lc = (tid & 7) * 4;
  int nrow = bi * 32 + lr;
  int crow = cj * 32 + lr;
  int cok = (crow < base);
  const float* ap = P + (size_t)nrow * N + lc;
  const float* bp = Vtr + (size_t)crow * N + lc;
  int kmax = (bi + 1) * 32;
  float4 a_c = *(const float4*)ap;
  float4 b_c = cok ? *(const float4*)bp : make_float4(0.f, 0.f, 0.f, 0.f);
  float acc[4] = {0.f, 0.f, 0.f, 0.f};
  for (int kb = 0; kb < kmax; kb += 32) {
    float4 a_n, b_n;
    if (kb + 32 < kmax) {
      a_n = *(const float4*)(ap + kb + 32);
      b_n = cok ? *(const float4*)(bp + kb + 32) : make_float4(0.f, 0.f, 0.f, 0.f);
    }
    float a4[4] = {a_c.x, a_c.y, a_c.z, a_c.w};
    if (first) {
#pragma unroll
      for (int j = 0; j < 4; ++j)
        a4[j] = 2.f * a4[j] - ((nrow == kb + lc + j) ? 1.f : 0.f);
    }
    As[lr * 33 + lc] = a4[0]; As[lr * 33 + lc + 1] = a4[1];
    As[lr * 33 + lc + 2] = a4[2]; As[lr * 33 + lc + 3] = a4[3];
    Bs[lr * 33 + lc] = b_c.x; Bs[lr * 33 + lc + 1] = b_c.y;
    Bs[lr * 33 + lc + 2] = b_c.z; Bs[lr * 33 + lc + 3] = b_c.w;
    __syncthreads();
#pragma unroll
    for (int kk = 0; kk < 32; ++kk) {
      float bv = Bs[tx * 33 + kk];
#pragma unroll
      for (int m = 0; m < 4; ++m) acc[m] += As[(ty + 8 * m) * 33 + kk] * bv;
    }
    __syncthreads();
    a_c = a_n; b_c = b_n;
  }
  int c = cj * 32 + tx;
  if (c < base) {
#pragma unroll
    for (int m = 0; m < 4; ++m)
      ast(&Vtr[(size_t)(base + c) * N + bi * 32 + ty + 8 * m], acc[m]);
  }
}

// W[base+q][c] = sum_k W[q][k] * P[k][c], q < base; K starts at cj*32
// (P[k][c]=0 for k<c, and those tiles are never written). Loads of W rows
// >= base suppressed.
__device__ void wstep_g(const float* __restrict__ P, float* __restrict__ W,
                        int base, int cj, int tid, float* sm) {
  float* As = sm;          // [32][33]  A[q][k]
  float* Bs = sm + 1056;   // [32][33]  B[k][c]
  int tx = tid & 31, ty = tid >> 5;
  int lr = tid >> 3, lc = (tid & 7) * 4;
  int qok = (lr < base);
  const float* ap = W + (size_t)lr * N + lc;
  const float* bp = P + cj * 32 + lc;
  int kb0 = cj * 32;
  float4 a_c = qok ? *(const float4*)(ap + kb0) : make_float4(0.f, 0.f, 0.f, 0.f);
  float4 b_c = *(const float4*)(bp + (size_t)(kb0 + lr) * N);
  float acc[4] = {0.f, 0.f, 0.f, 0.f};
  for (int kb = kb0; kb < N; kb += 32) {
    float4 a_n, b_n;
    if (kb + 32 < N) {
      a_n = qok ? *(const float4*)(ap + kb + 32) : make_float4(0.f, 0.f, 0.f, 0.f);
      b_n = *(const float4*)(bp + (size_t)(kb + 32 + lr) * N);
    }
    As[lr * 33 + lc] = a_c.x; As[lr * 33 + lc + 1] = a_c.y;
    As[lr * 33 + lc + 2] = a_c.z; As[lr * 33 + lc + 3] = a_c.w;
    Bs[lr * 33 + lc] = b_c.x; Bs[lr * 33 + lc + 1] = b_c.y;
    Bs[lr * 33 + lc + 2] = b_c.z; Bs[lr * 33 + lc + 3] = b_c.w;
    __syncthreads();
#pragma unroll
    for (int kk = 0; kk < 32; ++kk) {
      float bv = Bs[kk * 33 + tx];
#pragma unroll
      for (int m = 0; m < 4; ++m) acc[m] += As[(ty + 8 * m) * 33 + kk] * bv;
    }
    __syncthreads();
    a_c = a_n; b_c = b_n;
  }
#pragma unroll
  for (int m = 0; m < 4; ++m) {
    int q = ty + 8 * m;
    if (q < base) ast(&W[(size_t)(base + q) * N + cj * 32 + tx], acc[m]);
  }
}

// kvec[q][r] = sum_n W[q][n] * Vtr[r][n].  8 blocks (2x4 tiles of 32).
__device__ void kfinal_g(const float* __restrict__ W, const float* __restrict__ Vtr,
                         float* __restrict__ kvec, int bi, int bj, int tid, float* sm) {
  float* As = sm;
  float* Bs = sm + 1056;
  int tx = tid & 31, ty = tid >> 5;
  int lr = tid >> 3, lc = (tid & 7) * 4;
  const float* ap = W + (size_t)(bi * 32 + lr) * N + lc;
  const float* bp = Vtr + (size_t)(bj * 32 + lr) * N + lc;
  float4 a_c = *(const float4*)ap;
  float4 b_c = *(const float4*)bp;
  float acc[4] = {0.f, 0.f, 0.f, 0.f};
  for (int kb = 0; kb < N; kb += 32) {
    float4 a_n, b_n;
    if (kb + 32 < N) {
      a_n = *(const float4*)(ap + kb + 32);
      b_n = *(const float4*)(bp + kb + 32);
    }
    As[lr * 33 + lc] = a_c.x; As[lr * 33 + lc + 1] = a_c.y;
    As[lr * 33 + lc + 2] = a_c.z; As[lr * 33 + lc + 3] = a_c.w;
    Bs[lr * 33 + lc] = b_c.x; Bs[lr * 33 + lc + 1] = b_c.y;
    Bs[lr * 33 + lc + 2] = b_c.z; Bs[lr * 33 + lc + 3] = b_c.w;
    __syncthreads();
#pragma unroll
    for (int kk = 0; kk < 32; ++kk) {
      float bv = Bs[tx * 33 + kk];
#pragma unroll
      for (int m = 0; m < 4; ++m) acc[m] += As[(ty + 8 * m) * 33 + kk] * bv;
    }
    __syncthreads();
    a_c = a_n; b_c = b_n;
  }
#pragma unroll
  for (int m = 0; m < 4; ++m)
    ast(&kvec[(size_t)(bi * 32 + ty + 8 * m) * 128 + bj * 32 + tx], acc[m]);
}

// Vtr[0][n] = delta * (Xi * Bm)[n]: 64 blocks x 8 rows (2 per wave).
__device__ void bd1_body(const float* __restrict__ Xi, const float* __restrict__ Bm,
                         float delta, float* __restrict__ Vtr, int blk, int tid,
                         float* sm) {
  float* bs = sm;
  if (tid < 128) ((float4*)bs)[tid] = ((const float4*)Bm)[tid];
  __syncthreads();
  int w = tid >> 6, lane = tid & 63;
#pragma unroll
  for (int pass = 0; pass < 2; ++pass) {
    int row = blk * 8 + w * 2 + pass;
    const float* Xr = Xi + (size_t)row * N + lane * 8;
    float4 a0 = *(const float4*)Xr;
    float4 a1 = *(const float4*)(Xr + 4);
    const float* bp = bs + lane * 8;
    float acc = a0.x * bp[0] + a0.y * bp[1] + a0.z * bp[2] + a0.w * bp[3]
              + a1.x * bp[4] + a1.y * bp[5] + a1.z * bp[6] + a1.w * bp[7];
    acc += __shfl_xor(acc, 1, 64);
    acc += __shfl_xor(acc, 2, 64);
    acc += __shfl_xor(acc, 4, 64);
    acc += __shfl_xor(acc, 8, 64);
    acc += __shfl_xor(acc, 16, 64);
    acc += __shfl_xor(acc, 32, 64);
    if (lane == 0) ast(&Vtr[row], delta * acc);
  }
}

__device__ __forceinline__ void afrag_unit(const float* __restrict__ X,
                                           unsigned* __restrict__ Atab, int u) {
  int lane = u & 63;
  int f = u >> 6;
  int bt = f >> 8, ut = f & 255;
  int row = bt * 16 + (lane & 15);
  int u0 = ut * 32 + ((lane >> 4) << 3);
  const float* xp = X + (size_t)row * L + u0;
  unsigned short v[8];
#pragma unroll
  for (int e = 0; e < 8; ++e) v[e] = f2bf(xp[e]);
  unsigned* q = Atab + ((size_t)f * 64 + lane) * 4;
  astu(q, pack2(v[0], v[1])); astu(q + 1, pack2(v[2], v[3]));
  astu(q + 2, pack2(v[4], v[5])); astu(q + 3, pack2(v[6], v[7]));
}

__device__ __forceinline__ void bfrag_unit(const float* __restrict__ kvec,
                                           unsigned* __restrict__ Btab, int u) {
  int lane = u & 63;
  int si = u >> 6;
  int base = si * 16 + (lane & 15) - ((lane >> 4) << 3);
  unsigned short v[8];
#pragma unroll
  for (int e = 0; e < 8; ++e) {
    int idx = base - e;
    float x = (idx >= 0) ? kvec[idx] : 0.0f;
    v[e] = f2bf(x);
  }
  unsigned* q = Btab + ((size_t)si * 64 + lane) * 4;
  astu(q, pack2(v[0], v[1])); astu(q + 1, pack2(v[2], v[3]));
  astu(q + 2, pack2(v[4], v[5])); astu(q + 3, pack2(v[6], v[7]));
}

#define NB 168u

// --- fused serial chain: 168 blocks, 21 fence-free barriers -----------------
__global__ __launch_bounds__(256, 2) void k_chain(
    const float* __restrict__ A, const float* __restrict__ Bm,
    const float* __restrict__ C, const float* __restrict__ logd,
    float* __restrict__ Xi, float* __restrict__ U1, float* __restrict__ U2,
    float* __restrict__ U3, float* __restrict__ PB,
    float* __restrict__ Vtr, float* __restrict__ W, float* __restrict__ kvec,
    unsigned* bar) {
  __shared__ float sm[8704];
  int b = blockIdx.x, tid = threadIdx.x;
  float delta = get_delta(logd);
  float h = 0.5f * delta;
#define PBUF(i) (PB + (size_t)(i) * (N * N))

  // sq32 triangular tile index for b < 136
  int sbi = 0, srem = b;
  while (srem > sbi) { srem -= (sbi + 1); ++sbi; }
  int sbj = srem;  // valid when b < 136

  // PH0: diag inverses + zero strict-upper 64-tiles of Xi + W[0]=C
  if (b < 8) {
    diag64(A, h, Xi, b, tid, sm);
  } else if (b < 36) {
    int idx = b - 8, bi = 0, bj = 0, cnt = 0;
    for (int i = 0; i < 8; ++i)
      for (int j = i + 1; j < 8; ++j) { if (cnt == idx) { bi = i; bj = j; } ++cnt; }
    int r = tid >> 2, c0 = (tid & 3) * 16;
    float4 z = {0.f, 0.f, 0.f, 0.f};
#pragma unroll
    for (int q = 0; q < 16; q += 4)
      ast4(Xi + (size_t)(bi * 64 + r) * N + bj * 64 + c0 + q, z);
  } else if (b == 36) {
    for (int i = tid; i < N; i += 256) ast(&W[i], C[i]);
  }
  gsync(bar, 0, NB);
  // PH1/PH2: level 64 -> 128
  if (b < 16) {
    int g = b >> 2, t = b & 3;
    gemm32(A + (size_t)(128 * g + 64) * N + 128 * g, N,
           Xi + (size_t)(128 * g) * (N + 1), N,
           U1 + g * 4096, 64, t >> 1, t & 1, 64, 1.0f, tid, sm);
  }
  gsync(bar, 1, NB);
  if (b < 16) {
    int g = b >> 2, t = b & 3;
    gemm32(Xi + (size_t)(128 * g + 64) * (N + 1), N, U1 + g * 4096, 64,
           Xi + (size_t)(128 * g + 64) * N + 128 * g, N, t >> 1, t & 1, 64, h, tid, sm);
  }
  gsync(bar, 2, NB);
  // PH3/PH4: level 128 -> 256
  if (b < 32) {
    int g = b >> 4, t = b & 15;
    gemm32(A + (size_t)(256 * g + 128) * N + 256 * g, N,
           Xi + (size_t)(256 * g) * (N + 1), N,
           U2 + g * 16384, 128, t >> 2, t & 3, 128, 1.0f, tid, sm);
  }
  gsync(bar, 3, NB);
  if (b < 32) {
    int g = b >> 4, t = b & 15;
    gemm32(Xi + (size_t)(256 * g + 128) * (N + 1), N, U2 + g * 16384, 128,
           Xi + (size_t)(256 * g + 128) * N + 256 * g, N, t >> 2, t & 3, 128, h, tid, sm);
  }
  gsync(bar, 4, NB);
  // PH5/PH6: level 256 -> 512
  if (b < 64)
    gemm32(A + (size_t)256 * N, N, Xi, N, U3, 256, b >> 3, b & 7, 256, 1.0f, tid, sm);
  gsync(bar, 5, NB);
  if (b < 64)
    gemm32(Xi + (size_t)256 * (N + 1), N, U3, 256,
           Xi + (size_t)256 * N, N, b >> 3, b & 7, 256, h, tid, sm);
  gsync(bar, 6, NB);
  // PH7: Bd -> Vtr row 0
  if (b < 64) bd1_body(Xi, Bm, delta, Vtr, b, tid, sm);
  gsync(bar, 7, NB);
  // PH8..PH14: squaring chain + V doubling (P1 = 2*Xi - I virtual)
  if (b < 136) sq32(Xi, PBUF(0), sbi, sbj, 1, tid, sm);
  else if (b < 152) vstep_g(Xi, Vtr, 1, 1, b - 136, tid, sm);
  gsync(bar, 8, NB);
  if (b < 136) sq32(PBUF(0), PBUF(1), sbi, sbj, 0, tid, sm);
  else if (b < 152) vstep_g(PBUF(0), Vtr, 2, 0, b - 136, tid, sm);
  gsync(bar, 9, NB);
  if (b < 136) sq32(PBUF(1), PBUF(2), sbi, sbj, 0, tid, sm);
  else if (b < 152) vstep_g(PBUF(1), Vtr, 4, 0, b - 136, tid, sm);
  gsync(bar, 10, NB);
  if (b < 136) sq32(PBUF(2), PBUF(3), sbi, sbj, 0, tid, sm);
  else if (b < 152) vstep_g(PBUF(2), Vtr, 8, 0, b - 136, tid, sm);
  gsync(bar, 11, NB);
  if (b < 136) sq32(PBUF(3), PBUF(4), sbi, sbj, 0, tid, sm);
  else if (b < 152) vstep_g(PBUF(3), Vtr, 16, 0, b - 136, tid, sm);
  gsync(bar, 12, NB);
  if (b < 136) sq32(PBUF(4), PBUF(5), sbi, sbj, 0, tid, sm);
  else if (b < 152) vstep_g(PBUF(4), Vtr, 32, 0, b - 136, tid, sm);
  gsync(bar, 13, NB);
  if (b < 136) sq32(PBUF(5), PBUF(6), sbi, sbj, 0, tid, sm);
  else vstep_g(PBUF(5), Vtr, 64, 0, b - 136, tid, sm);   // 32 blocks
  gsync(bar, 14, NB);
  // PH15..PH19: squaring chain + W doubling
  if (b < 136) sq32(PBUF(6), PBUF(7), sbi, sbj, 0, tid, sm);
  else if (b < 152) wstep_g(PBUF(6), W, 1, b - 136, tid, sm);
  gsync(bar, 15, NB);
  if (b < 136) sq32(PBUF(7), PBUF(8), sbi, sbj, 0, tid, sm);
  else if (b < 152) wstep_g(PBUF(7), W, 2, b - 136, tid, sm);
  gsync(bar, 16, NB);
  if (b < 136) sq32(PBUF(8), PBUF(9), sbi, sbj, 0, tid, sm);
  else if (b < 152) wstep_g(PBUF(8), W, 4, b - 136, tid, sm);
  gsync(bar, 17, NB);
  if (b < 136) sq32(PBUF(9), PBUF(10), sbi, sbj, 0, tid, sm);
  else if (b < 152) wstep_g(PBUF(9), W, 8, b - 136, tid, sm);
  gsync(bar, 18, NB);
  if (b < 136) sq32(PBUF(10), PBUF(11), sbi, sbj, 0, tid, sm);
  else if (b < 152) wstep_g(PBUF(10), W, 16, b - 136, tid, sm);
  gsync(bar, 19, NB);
  // PH20: last W doubling (P = Ad^4096)
  if (b >= 136 && b < 152) wstep_g(PBUF(11), W, 32, b - 136, tid, sm);
  gsync(bar, 20, NB);
  // PH21: kvec = W * Vtr^T
  if (b < 8) kfinal_g(W, Vtr, kvec, b >> 2, b & 3, tid, sm);
#undef PBUF
}

// Prologue: fill Atab/Btab (256 blocks, write-through), fence-free grid sync,
// then balanced Toeplitz conv: block p handles t-tile pair (p, 511-p).
__global__ __launch_bounds__(256, 2) void k_convmm(unsigned* __restrict__ AtabW,
                                                   unsigned* __restrict__ BtabW,
                                                   const float* __restrict__ kvec,
                                                   const float* __restrict__ X,
                                                   const float* __restrict__ Dp,
                                                   float* __restrict__ Y,
                                                   unsigned* bar) {
  __shared__ short8 bsh[32][64];
  int tid = threadIdx.x, lane = tid & 63, bt = tid >> 6;
  int p = blockIdx.x;
  afrag_unit(X, AtabW, p * 256 + tid);
  if (p < 128) bfrag_unit(kvec, BtabW, p * 256 + tid);
  gsync(bar, 0, 256);
  const short8* Atab = (const short8*)AtabW;
  const short8* Btab = (const short8*)BtabW;
  int jL = p, jH = 511 - p;
  int nL = (jL + 2) >> 1, nH = (jH + 2) >> 1;
  f32x4 aL = {0.f, 0.f, 0.f, 0.f}, aH = {0.f, 0.f, 0.f, 0.f};
  const short8* Abase = Atab + (size_t)bt * 256 * 64 + lane;
  for (int u0 = 0; u0 < nH; u0 += 16) {
#pragma unroll
    for (int k = 0; k < 8; ++k) {
      int idx = tid + 256 * k;
      int f = idx >> 6, ln = idx & 63;
      int i = f & 15;
      int ut = u0 + i;
      if (f < 16) {
        if (ut < nH) bsh[i][ln] = Btab[(size_t)(jH - 2 * ut) * 64 + ln];
      } else {
        if (ut < nL) bsh[16 + i][ln] = Btab[(size_t)(jL - 2 * ut) * 64 + ln];
      }
    }
    __syncthreads();
    int m = (nH - u0 < 16) ? (nH - u0) : 16;
    for (int i = 0; i < m; ++i) {
      short8 a = Abase[(size_t)(u0 + i) * 64];
      aH = __builtin_amdgcn_mfma_f32_16x16x32_bf16(a, bsh[i][lane], aH, 0, 0, 0);
      if (u0 + i < nL)
        aL = __builtin_amdgcn_mfma_f32_16x16x32_bf16(a, bsh[16 + i][lane], aL, 0, 0, 0);
    }
    __syncthreads();
  }
  float D0 = Dp[0];
  int tt = lane & 15, rq = (lane >> 4) << 2;
#pragma unroll
  for (int r = 0; r < 4; ++r) {
    int bb = bt * 16 + rq + r;
    size_t oL = (size_t)bb * L + jL * 16 + tt;
    size_t oH = (size_t)bb * L + jH * 16 + tt;
    Y[oL] = aL[r] + D0 * X[oL];
    Y[oH] = aH[r] + D0 * X[oH];
  }
}

extern "C" void kernel_launch(void* const* d_in, const int* in_sizes, int n_in,
                              void* d_out, int out_size, void* d_ws, size_t ws_size,
                              hipStream_t stream) {
  const float* X  = (const float*)d_in[0];
  const float* A  = (const float*)d_in[1];
  const float* Bm = (const float*)d_in[2];
  const float* C  = (const float*)d_in[3];
  const float* D  = (const float*)d_in[4];
  const float* ld = (const float*)d_in[5];
  float* Y = (float*)d_out;

  float* ws = (float*)d_ws;
  unsigned* bar = (unsigned*)ws;        // 64 u32
  float* kv  = ws + 64;                 // 8192
  float* Vtr = ws + 8256;               // 128*512
  float* W   = ws + 73792;              // 64*512
  float* Xi  = ws + 106560;             // 512*512
  float* U1  = ws + 368704;             // 4*64*64
  float* U2  = ws + 385088;             // 2*128*128
  float* U3  = ws + 417856;             // 256*256
  float* PB  = ws + 483392;             // 12*512*512
  unsigned* Atab = (unsigned*)Xi;       // conv-dispatch only
  unsigned* Btab = (unsigned*)PB;       // conv-dispatch only

  hipMemsetAsync(bar, 0, 64 * sizeof(unsigned), stream);
  k_chain<<<168, 256, 0, stream>>>(A, Bm, C, ld, Xi, U1, U2, U3, PB, Vtr, W, kv, bar);
  k_convmm<<<256, 256, 0, stream>>>(Atab, Btab, kv, X, D, Y, bar + 32);
}

// Round 10
// 505.686 us; speedup vs baseline: 5.4082x; 1.1254x over previous
//
#include <hip/hip_runtime.h>

#define N 512
#define L 8192

#define LOG_MIN -6.907755278982137f
#define LOG_MAX -2.302585092994046f

typedef __attribute__((ext_vector_type(8))) short short8;
typedef __attribute__((ext_vector_type(4))) float f32x4;

__device__ __forceinline__ float get_delta(const float* logd) {
  float ld = logd[0];
  ld = fminf(fmaxf(ld, LOG_MIN), LOG_MAX);
  return expf(ld);
}
__device__ __forceinline__ unsigned short f2bf(float x) {
  union { float f; unsigned int u; } c; c.f = x;
  unsigned int u = c.u;
  u += 0x7FFFu + ((u >> 16) & 1u);
  return (unsigned short)(u >> 16);
}
__device__ __forceinline__ unsigned int pack2(unsigned short a, unsigned short b) {
  return (unsigned int)a | ((unsigned int)b << 16);
}

// Agent-visible write-through stores (sc1). Cross-XCD safe without fences
// under the line-granular write-once discipline (see ws layout).
__device__ __forceinline__ void ast(float* p, float v) {
  __hip_atomic_store(p, v, __ATOMIC_RELAXED, __HIP_MEMORY_SCOPE_AGENT);
}
__device__ __forceinline__ void ast4(float* p, float4 v) {
  ast(p, v.x); ast(p + 1, v.y); ast(p + 2, v.z); ast(p + 3, v.w);
}
__device__ __forceinline__ void astu(unsigned* p, unsigned v) {
  __hip_atomic_store(p, v, __ATOMIC_RELAXED, __HIP_MEMORY_SCOPE_AGENT);
}

// Fence-free grid barrier: drain stores (vmcnt0), relaxed add + relaxed poll.
__device__ __forceinline__ void gsync(unsigned* bar, int p, unsigned tgt) {
  asm volatile("s_waitcnt vmcnt(0)" ::: "memory");
  __syncthreads();
  if (threadIdx.x == 0) {
    __hip_atomic_fetch_add(&bar[p], 1u, __ATOMIC_RELAXED, __HIP_MEMORY_SCOPE_AGENT);
    while (__hip_atomic_load(&bar[p], __ATOMIC_RELAXED, __HIP_MEMORY_SCOPE_AGENT) < tgt)
      __builtin_amdgcn_s_sleep(2);
  }
  __syncthreads();
}

// ---------------------------------------------------------------------------
// ws layout (floats). Write-once per address inside k_chain; no address is
// read before its single write (cache-line granular).
//   0        bar   (64 u32)
//   64       kvec  (8192)
//   8256     Vtr   (128*512)   Vtr[r][n] = (Ad^r Bd)[n]
//   73792    W     (64*512)
//   106560   Xi    (512*512)   A1^-1
//   368704   U1 / 385088 U2 / 417856 U3
//   483392   PB[12] 12*512*512  Ad^2..Ad^4096 (lower+diag tiles only)
//   3629120  Atab  (1MB bf16 A-frags)   written PH0, read by conv
//   3891264  Btab  (512KB bf16 B-frags) written PH22, read by conv
// ---------------------------------------------------------------------------

__device__ void diag64(const float* __restrict__ A, float h,
                       float* __restrict__ Xi, int blk, int tid, float* sm) {
  float* Ash = sm;          // [64][65]
  float* xs  = sm + 4160;   // [64][65]
  float* dinv = sm + 8320;  // [64]
  int i0 = blk * 64;
  int r = tid >> 2, c0 = (tid & 3) * 16;
#pragma unroll
  for (int q = 0; q < 16; q += 4) {
    float4 v = *(const float4*)(A + (size_t)(i0 + r) * N + i0 + c0 + q);
    Ash[r * 65 + c0 + q] = v.x; Ash[r * 65 + c0 + q + 1] = v.y;
    Ash[r * 65 + c0 + q + 2] = v.z; Ash[r * 65 + c0 + q + 3] = v.w;
  }
  for (int i = tid; i < 4160; i += 256) xs[i] = 0.f;
  __syncthreads();
  if (tid < 64) dinv[tid] = 1.f / (1.f - h * Ash[tid * 65 + tid]);
  __syncthreads();
  int t = tid >> 2, sub = tid & 3;
  for (int rr = 0; rr < 64; ++rr) {
    if (t <= rr) {
      float s = 0.f;
      for (int k = t + sub; k < rr; k += 4) s += Ash[rr * 65 + k] * xs[k * 65 + t];
      s += __shfl_xor(s, 1, 64);
      s += __shfl_xor(s, 2, 64);
      if (sub == 0)
        xs[rr * 65 + t] = (((rr == t) ? 1.f : 0.f) + h * s) * dinv[rr];
    }
  }
  __syncthreads();
#pragma unroll
  for (int q = 0; q < 16; q += 4) {
    float4 v = {xs[r * 65 + c0 + q], xs[r * 65 + c0 + q + 1],
                xs[r * 65 + c0 + q + 2], xs[r * 65 + c0 + q + 3]};
    ast4(Xi + (size_t)(i0 + r) * N + i0 + c0 + q, v);
  }
}

// All-K-upfront 32x32-tile GEMM, NT k-tiles. One latency for the whole phase.
template <int NT>
__device__ void gemm32t(const float* __restrict__ A_, int lda,
                        const float* __restrict__ B_, int ldb,
                        float* __restrict__ C_, int ldc,
                        int bi, int bj, float alpha, int tid, float* sm) {
  float* As = sm;          // [32][33]
  float* Bs = sm + 1056;   // [32][33]
  int tx = tid & 31, ty = tid >> 5;
  int lr = tid >> 3, lc = (tid & 7) * 4;
  const float* ap = A_ + (size_t)(bi * 32 + lr) * lda + lc;
  const float* bp = B_ + (size_t)lr * ldb + bj * 32 + lc;
  float4 aR[NT], bR[NT];
#pragma unroll
  for (int t = 0; t < NT; ++t) {
    aR[t] = *(const float4*)(ap + 32 * t);
    bR[t] = *(const float4*)(bp + (size_t)(32 * t) * ldb);
  }
  float acc[4] = {0.f, 0.f, 0.f, 0.f};
#pragma unroll
  for (int t = 0; t < NT; ++t) {
    As[lr * 33 + lc] = aR[t].x; As[lr * 33 + lc + 1] = aR[t].y;
    As[lr * 33 + lc + 2] = aR[t].z; As[lr * 33 + lc + 3] = aR[t].w;
    Bs[lr * 33 + lc] = bR[t].x; Bs[lr * 33 + lc + 1] = bR[t].y;
    Bs[lr * 33 + lc + 2] = bR[t].z; Bs[lr * 33 + lc + 3] = bR[t].w;
    __syncthreads();
#pragma unroll
    for (int kk = 0; kk < 32; ++kk) {
      float bv = Bs[kk * 33 + tx];
#pragma unroll
      for (int m = 0; m < 4; ++m) acc[m] += As[(ty + 8 * m) * 33 + kk] * bv;
    }
    __syncthreads();
  }
#pragma unroll
  for (int m = 0; m < 4; ++m)
    ast(&C_[(size_t)(bi * 32 + ty + 8 * m) * ldc + bj * 32 + tx], alpha * acc[m]);
}

// 32x32-tile lower-tri squaring, all K loads issued upfront (uniform nk).
__device__ void sq32(const float* __restrict__ P, float* __restrict__ Q,
                     int bi, int bj, int first, int tid, float* sm) {
  float* As = sm;
  float* Bs = sm + 1056;
  int tx = tid & 31, ty = tid >> 5;
  int lr = tid >> 3, lc = (tid & 7) * 4;
  int nk = bi - bj + 1;          // 1..16, block-uniform
  int kb0 = bj * 32;
  int arow = bi * 32 + lr;
  const float* ap = P + (size_t)arow * N + lc;
  const float* bp = P + bj * 32 + lc;
  float4 aR[16], bR[16];
#pragma unroll
  for (int t = 0; t < 16; ++t) {
    if (t < nk) {
      int kt = kb0 + 32 * t;
      aR[t] = *(const float4*)(ap + kt);
      bR[t] = *(const float4*)(bp + (size_t)(kt + lr) * N);
    }
  }
  float acc[4] = {0.f, 0.f, 0.f, 0.f};
#pragma unroll
  for (int t = 0; t < 16; ++t) {
    if (t < nk) {
      int kb = kb0 + 32 * t;
      float a4[4] = {aR[t].x, aR[t].y, aR[t].z, aR[t].w};
      float b4[4] = {bR[t].x, bR[t].y, bR[t].z, bR[t].w};
      if (first) {
#pragma unroll
        for (int j = 0; j < 4; ++j) {
          a4[j] = 2.f * a4[j] - ((arow == kb + lc + j) ? 1.f : 0.f);
          b4[j] = 2.f * b4[j] - ((kb + lr == bj * 32 + lc + j) ? 1.f : 0.f);
        }
      }
      As[lr * 33 + lc] = a4[0]; As[lr * 33 + lc + 1] = a4[1];
      As[lr * 33 + lc + 2] = a4[2]; As[lr * 33 + lc + 3] = a4[3];
      Bs[lr * 33 + lc] = b4[0]; Bs[lr * 33 + lc + 1] = b4[1];
      Bs[lr * 33 + lc + 2] = b4[2]; Bs[lr * 33 + lc + 3] = b4[3];
      __syncthreads();
#pragma unroll
      for (int kk = 0; kk < 32; ++kk) {
        float bv = Bs[kk * 33 + tx];
#pragma unroll
        for (int m = 0; m < 4; ++m) acc[m] += As[(ty + 8 * m) * 33 + kk] * bv;
      }
      __syncthreads();
    }
  }
#pragma unroll
  for (int m = 0; m < 4; ++m)
    ast(&Q[(size_t)(bi * 32 + ty + 8 * m) * N + bj * 32 + tx], acc[m]);
}

// Vtr[base+c][n] = sum_k P[n][k]*Vtr[c][k], all loads upfront.
__device__ void vstep_g(const float* __restrict__ P, float* __restrict__ Vtr,
                        int base, int first, int idx, int tid, float* sm) {
  int bi = idx & 15, cj = idx >> 4;
  float* As = sm;
  float* Bs = sm + 1056;
  int tx = tid & 31, ty = tid >> 5;
  int lr = tid >> 3, lc = (tid & 7) * 4;
  int nrow = bi * 32 + lr;
  int crow = cj * 32 + lr;
  int cok = (crow < base);
  const float* ap = P + (size_t)nrow * N + lc;
  const float* bp = Vtr + (size_t)crow * N + lc;
  int nk = bi + 1;               // 1..16
  float4 aR[16], bR[16];
#pragma unroll
  for (int t = 0; t < 16; ++t) {
    if (t < nk) {
      aR[t] = *(const float4*)(ap + 32 * t);
      bR[t] = cok ? *(const float4*)(bp + 32 * t) : make_float4(0.f, 0.f, 0.f, 0.f);
    }
  }
  float acc[4] = {0.f, 0.f, 0.f, 0.f};
#pragma unroll
  for (int t = 0; t < 16; ++t) {
    if (t < nk) {
      int kb = 32 * t;
      float a4[4] = {aR[t].x, aR[t].y, aR[t].z, aR[t].w};
      if (first) {
#pragma unroll
        for (int j = 0; j < 4; ++j)
          a4[j] = 2.f * a4[j] - ((nrow == kb + lc + j) ? 1.f : 0.f);
      }
      As[lr * 33 + lc] = a4[0]; As[lr * 33 + lc + 1] = a4[1];
      As[lr * 33 + lc + 2] = a4[2]; As[lr * 33 + lc + 3] = a4[3];
      Bs[lr * 33 + lc] = bR[t].x; Bs[lr * 33 + lc + 1] = bR[t].y;
      Bs[lr * 33 + lc + 2] = bR[t].z; Bs[lr * 33 + lc + 3] = bR[t].w;
      __syncthreads();
#pragma unroll
      for (int kk = 0; kk < 32; ++kk) {
        float bv = Bs[tx * 33 + kk];
#pragma unroll
        for (int m = 0; m < 4; ++m) acc[m] += As[(ty + 8 * m) * 33 + kk] * bv;
      }
      __syncthreads();
    }
  }
  int c = cj * 32 + tx;
  if (c < base) {
#pragma unroll
    for (int m = 0; m < 4; ++m)
      ast(&Vtr[(size_t)(base + c) * N + bi * 32 + ty + 8 * m], acc[m]);
  }
}

// W[base+q][c] = sum_k W[q][k]*P[k][c], K from cj*32, all loads upfront.
__device__ void wstep_g(const float* __restrict__ P, float* __restrict__ W,
                        int base, int cj, int tid, float* sm) {
  float* As = sm;
  float* Bs = sm + 1056;
  int tx = tid & 31, ty = tid >> 5;
  int lr = tid >> 3, lc = (tid & 7) * 4;
  int qok = (lr < base);
  const float* ap = W + (size_t)lr * N + lc;
  const float* bp = P + cj * 32 + lc;
  int kb0 = cj * 32;
  int nk = 16 - cj;              // 1..16
  float4 aR[16], bR[16];
#pragma unroll
  for (int t = 0; t < 16; ++t) {
    if (t < nk) {
      int kt = kb0 + 32 * t;
      aR[t] = qok ? *(const float4*)(ap + kt) : make_float4(0.f, 0.f, 0.f, 0.f);
      bR[t] = *(const float4*)(bp + (size_t)(kt + lr) * N);
    }
  }
  float acc[4] = {0.f, 0.f, 0.f, 0.f};
#pragma unroll
  for (int t = 0; t < 16; ++t) {
    if (t < nk) {
      As[lr * 33 + lc] = aR[t].x; As[lr * 33 + lc + 1] = aR[t].y;
      As[lr * 33 + lc + 2] = aR[t].z; As[lr * 33 + lc + 3] = aR[t].w;
      Bs[lr * 33 + lc] = bR[t].x; Bs[lr * 33 + lc + 1] = bR[t].y;
      Bs[lr * 33 + lc + 2] = bR[t].z; Bs[lr * 33 + lc + 3] = bR[t].w;
      __syncthreads();
#pragma unroll
      for (int kk = 0; kk < 32; ++kk) {
        float bv = Bs[kk * 33 + tx];
#pragma unroll
        for (int m = 0; m < 4; ++m) acc[m] += As[(ty + 8 * m) * 33 + kk] * bv;
      }
      __syncthreads();
    }
  }
#pragma unroll
  for (int m = 0; m < 4; ++m) {
    int q = ty + 8 * m;
    if (q < base) ast(&W[(size_t)(base + q) * N + cj * 32 + tx], acc[m]);
  }
}

// kvec[q][r] = sum_n W[q][n]*Vtr[r][n], 16 tiles, all loads upfront.
__device__ void kfinal_g(const float* __restrict__ W, const float* __restrict__ Vtr,
                         float* __restrict__ kvec, int bi, int bj, int tid, float* sm) {
  float* As = sm;
  float* Bs = sm + 1056;
  int tx = tid & 31, ty = tid >> 5;
  int lr = tid >> 3, lc = (tid & 7) * 4;
  const float* ap = W + (size_t)(bi * 32 + lr) * N + lc;
  const float* bp = Vtr + (size_t)(bj * 32 + lr) * N + lc;
  float4 aR[16], bR[16];
#pragma unroll
  for (int t = 0; t < 16; ++t) {
    aR[t] = *(const float4*)(ap + 32 * t);
    bR[t] = *(const float4*)(bp + 32 * t);
  }
  float acc[4] = {0.f, 0.f, 0.f, 0.f};
#pragma unroll
  for (int t = 0; t < 16; ++t) {
    As[lr * 33 + lc] = aR[t].x; As[lr * 33 + lc + 1] = aR[t].y;
    As[lr * 33 + lc + 2] = aR[t].z; As[lr * 33 + lc + 3] = aR[t].w;
    Bs[lr * 33 + lc] = bR[t].x; Bs[lr * 33 + lc + 1] = bR[t].y;
    Bs[lr * 33 + lc + 2] = bR[t].z; Bs[lr * 33 + lc + 3] = bR[t].w;
    __syncthreads();
#pragma unroll
    for (int kk = 0; kk < 32; ++kk) {
      float bv = Bs[tx * 33 + kk];
#pragma unroll
      for (int m = 0; m < 4; ++m) acc[m] += As[(ty + 8 * m) * 33 + kk] * bv;
    }
    __syncthreads();
  }
#pragma unroll
  for (int m = 0; m < 4; ++m)
    ast(&kvec[(size_t)(bi * 32 + ty + 8 * m) * 128 + bj * 32 + tx], acc[m]);
}

__device__ void bd1_body(const float* __restrict__ Xi, const float* __restrict__ Bm,
                         float delta, float* __restrict__ Vtr, int blk, int tid,
                         float* sm) {
  float* bs = sm;
  if (tid < 128) ((float4*)bs)[tid] = ((const float4*)Bm)[tid];
  __syncthreads();
  int w = tid >> 6, lane = tid & 63;
#pragma unroll
  for (int pass = 0; pass < 2; ++pass) {
    int row = blk * 8 + w * 2 + pass;
    const float* Xr = Xi + (size_t)row * N + lane * 8;
    float4 a0 = *(const float4*)Xr;
    float4 a1 = *(const float4*)(Xr + 4);
    const float* bp = bs + lane * 8;
    float acc = a0.x * bp[0] + a0.y * bp[1] + a0.z * bp[2] + a0.w * bp[3]
              + a1.x * bp[4] + a1.y * bp[5] + a1.z * bp[6] + a1.w * bp[7];
    acc += __shfl_xor(acc, 1, 64);
    acc += __shfl_xor(acc, 2, 64);
    acc += __shfl_xor(acc, 4, 64);
    acc += __shfl_xor(acc, 8, 64);
    acc += __shfl_xor(acc, 16, 64);
    acc += __shfl_xor(acc, 32, 64);
    if (lane == 0) ast(&Vtr[row], delta * acc);
  }
}

__device__ __forceinline__ void afrag_unit(const float* __restrict__ X,
                                           unsigned* __restrict__ Atab, int u) {
  int lane = u & 63;
  int f = u >> 6;
  int bt = f >> 8, ut = f & 255;
  int row = bt * 16 + (lane & 15);
  int u0 = ut * 32 + ((lane >> 4) << 3);
  const float* xp = X + (size_t)row * L + u0;
  unsigned short v[8];
#pragma unroll
  for (int e = 0; e < 8; ++e) v[e] = f2bf(xp[e]);
  unsigned* q = Atab + ((size_t)f * 64 + lane) * 4;
  astu(q, pack2(v[0], v[1])); astu(q + 1, pack2(v[2], v[3]));
  astu(q + 2, pack2(v[4], v[5])); astu(q + 3, pack2(v[6], v[7]));
}

__device__ __forceinline__ void bfrag_unit(const float* __restrict__ kvec,
                                           unsigned* __restrict__ Btab, int u) {
  int lane = u & 63;
  int si = u >> 6;
  int base = si * 16 + (lane & 15) - ((lane >> 4) << 3);
  unsigned short v[8];
#pragma unroll
  for (int e = 0; e < 8; ++e) {
    int idx = base - e;
    float x = (idx >= 0) ? kvec[idx] : 0.0f;
    v[e] = f2bf(x);
  }
  unsigned* q = Btab + ((size_t)si * 64 + lane) * 4;
  astu(q, pack2(v[0], v[1])); astu(q + 1, pack2(v[2], v[3]));
  astu(q + 2, pack2(v[4], v[5])); astu(q + 3, pack2(v[6], v[7]));
}

#define NB 168u

// --- fused serial chain: 168 blocks, 22 fence-free barriers -----------------
__global__ __launch_bounds__(256, 2) void k_chain(
    const float* __restrict__ A, const float* __restrict__ Bm,
    const float* __restrict__ C, const float* __restrict__ logd,
    const float* __restrict__ X,
    float* __restrict__ Xi, float* __restrict__ U1, float* __restrict__ U2,
    float* __restrict__ U3, float* __restrict__ PB,
    float* __restrict__ Vtr, float* __restrict__ W, float* __restrict__ kvec,
    unsigned* __restrict__ Atab, unsigned* __restrict__ Btab,
    unsigned* bar) {
  __shared__ float sm[8704];
  int b = blockIdx.x, tid = threadIdx.x;
  float delta = get_delta(logd);
  float h = 0.5f * delta;
#define PBUF(i) (PB + (size_t)(i) * (N * N))

  // sq32 triangular tile index for b < 136
  int sbi = 0, srem = b;
  while (srem > sbi) { srem -= (sbi + 1); ++sbi; }
  int sbj = srem;

  // PH0: diag inverses + zero strict-upper Xi + W[0]=C + Atab fill
  if (b < 8) {
    diag64(A, h, Xi, b, tid, sm);
  } else if (b < 36) {
    int idx = b - 8, bi = 0, bj = 0, cnt = 0;
    for (int i = 0; i < 8; ++i)
      for (int j = i + 1; j < 8; ++j) { if (cnt == idx) { bi = i; bj = j; } ++cnt; }
    int r = tid >> 2, c0 = (tid & 3) * 16;
    float4 z = {0.f, 0.f, 0.f, 0.f};
#pragma unroll
    for (int q = 0; q < 16; q += 4)
      ast4(Xi + (size_t)(bi * 64 + r) * N + bj * 64 + c0 + q, z);
  } else if (b == 36) {
    for (int i = tid; i < N; i += 256) ast(&W[i], C[i]);
  } else if (b >= 40) {
    int base = (b - 40) * 512;
    afrag_unit(X, Atab, base + tid);
    afrag_unit(X, Atab, base + 256 + tid);
  }
  gsync(bar, 0, NB);
  // PH1/PH2: level 64 -> 128
  if (b < 16) {
    int g = b >> 2, t = b & 3;
    gemm32t<2>(A + (size_t)(128 * g + 64) * N + 128 * g, N,
               Xi + (size_t)(128 * g) * (N + 1), N,
               U1 + g * 4096, 64, t >> 1, t & 1, 1.0f, tid, sm);
  }
  gsync(bar, 1, NB);
  if (b < 16) {
    int g = b >> 2, t = b & 3;
    gemm32t<2>(Xi + (size_t)(128 * g + 64) * (N + 1), N, U1 + g * 4096, 64,
               Xi + (size_t)(128 * g + 64) * N + 128 * g, N, t >> 1, t & 1, h, tid, sm);
  }
  gsync(bar, 2, NB);
  // PH3/PH4: level 128 -> 256
  if (b < 32) {
    int g = b >> 4, t = b & 15;
    gemm32t<4>(A + (size_t)(256 * g + 128) * N + 256 * g, N,
               Xi + (size_t)(256 * g) * (N + 1), N,
               U2 + g * 16384, 128, t >> 2, t & 3, 1.0f, tid, sm);
  }
  gsync(bar, 3, NB);
  if (b < 32) {
    int g = b >> 4, t = b & 15;
    gemm32t<4>(Xi + (size_t)(256 * g + 128) * (N + 1), N, U2 + g * 16384, 128,
               Xi + (size_t)(256 * g + 128) * N + 256 * g, N, t >> 2, t & 3, h, tid, sm);
  }
  gsync(bar, 4, NB);
  // PH5/PH6: level 256 -> 512
  if (b < 64)
    gemm32t<8>(A + (size_t)256 * N, N, Xi, N, U3, 256, b >> 3, b & 7, 1.0f, tid, sm);
  gsync(bar, 5, NB);
  if (b < 64)
    gemm32t<8>(Xi + (size_t)256 * (N + 1), N, U3, 256,
               Xi + (size_t)256 * N, N, b >> 3, b & 7, h, tid, sm);
  gsync(bar, 6, NB);
  // PH7: Bd -> Vtr row 0
  if (b < 64) bd1_body(Xi, Bm, delta, Vtr, b, tid, sm);
  gsync(bar, 7, NB);
  // PH8..PH14: squaring chain + V doubling (P1 = 2*Xi - I virtual)
  if (b < 136) sq32(Xi, PBUF(0), sbi, sbj, 1, tid, sm);
  else if (b < 152) vstep_g(Xi, Vtr, 1, 1, b - 136, tid, sm);
  gsync(bar, 8, NB);
  if (b < 136) sq32(PBUF(0), PBUF(1), sbi, sbj, 0, tid, sm);
  else if (b < 152) vstep_g(PBUF(0), Vtr, 2, 0, b - 136, tid, sm);
  gsync(bar, 9, NB);
  if (b < 136) sq32(PBUF(1), PBUF(2), sbi, sbj, 0, tid, sm);
  else if (b < 152) vstep_g(PBUF(1), Vtr, 4, 0, b - 136, tid, sm);
  gsync(bar, 10, NB);
  if (b < 136) sq32(PBUF(2), PBUF(3), sbi, sbj, 0, tid, sm);
  else if (b < 152) vstep_g(PBUF(2), Vtr, 8, 0, b - 136, tid, sm);
  gsync(bar, 11, NB);
  if (b < 136) sq32(PBUF(3), PBUF(4), sbi, sbj, 0, tid, sm);
  else if (b < 152) vstep_g(PBUF(3), Vtr, 16, 0, b - 136, tid, sm);
  gsync(bar, 12, NB);
  if (b < 136) sq32(PBUF(4), PBUF(5), sbi, sbj, 0, tid, sm);
  else if (b < 152) vstep_g(PBUF(4), Vtr, 32, 0, b - 136, tid, sm);
  gsync(bar, 13, NB);
  if (b < 136) sq32(PBUF(5), PBUF(6), sbi, sbj, 0, tid, sm);
  else vstep_g(PBUF(5), Vtr, 64, 0, b - 136, tid, sm);   // 32 blocks
  gsync(bar, 14, NB);
  // PH15..PH19: squaring chain + W doubling
  if (b < 136) sq32(PBUF(6), PBUF(7), sbi, sbj, 0, tid, sm);
  else if (b < 152) wstep_g(PBUF(6), W, 1, b - 136, tid, sm);
  gsync(bar, 15, NB);
  if (b < 136) sq32(PBUF(7), PBUF(8), sbi, sbj, 0, tid, sm);
  else if (b < 152) wstep_g(PBUF(7), W, 2, b - 136, tid, sm);
  gsync(bar, 16, NB);
  if (b < 136) sq32(PBUF(8), PBUF(9), sbi, sbj, 0, tid, sm);
  else if (b < 152) wstep_g(PBUF(8), W, 4, b - 136, tid, sm);
  gsync(bar, 17, NB);
  if (b < 136) sq32(PBUF(9), PBUF(10), sbi, sbj, 0, tid, sm);
  else if (b < 152) wstep_g(PBUF(9), W, 8, b - 136, tid, sm);
  gsync(bar, 18, NB);
  if (b < 136) sq32(PBUF(10), PBUF(11), sbi, sbj, 0, tid, sm);
  else if (b < 152) wstep_g(PBUF(10), W, 16, b - 136, tid, sm);
  gsync(bar, 19, NB);
  // PH20: last W doubling (P = Ad^4096)
  if (b >= 136 && b < 152) wstep_g(PBUF(11), W, 32, b - 136, tid, sm);
  gsync(bar, 20, NB);
  // PH21: kvec = W * Vtr^T
  if (b < 8) kfinal_g(W, Vtr, kvec, b >> 2, b & 3, tid, sm);
  gsync(bar, 21, NB);
  // PH22: Toeplitz B-frags (visibility to conv via kernel boundary)
  if (b < 128) bfrag_unit(kvec, Btab, b * 256 + tid);
#undef PBUF
}

// Balanced Toeplitz conv: block p handles t-tile pair (p, 511-p). No prologue.
__global__ __launch_bounds__(256, 2) void k_convmm(const short8* __restrict__ Atab,
                                                   const short8* __restrict__ Btab,
                                                   const float* __restrict__ X,
                                                   const float* __restrict__ Dp,
                                                   float* __restrict__ Y) {
  __shared__ short8 bsh[32][64];
  int tid = threadIdx.x, lane = tid & 63, bt = tid >> 6;
  int p = blockIdx.x;
  int jL = p, jH = 511 - p;
  int nL = (jL + 2) >> 1, nH = (jH + 2) >> 1;
  f32x4 aL = {0.f, 0.f, 0.f, 0.f}, aH = {0.f, 0.f, 0.f, 0.f};
  const short8* Abase = Atab + (size_t)bt * 256 * 64 + lane;
  for (int u0 = 0; u0 < nH; u0 += 16) {
#pragma unroll
    for (int k = 0; k < 8; ++k) {
      int idx = tid + 256 * k;
      int f = idx >> 6, ln = idx & 63;
      int i = f & 15;
      int ut = u0 + i;
      if (f < 16) {
        if (ut < nH) bsh[i][ln] = Btab[(size_t)(jH - 2 * ut) * 64 + ln];
      } else {
        if (ut < nL) bsh[16 + i][ln] = Btab[(size_t)(jL - 2 * ut) * 64 + ln];
      }
    }
    __syncthreads();
    int m = (nH - u0 < 16) ? (nH - u0) : 16;
    short8 a = Abase[(size_t)u0 * 64];
    for (int i = 0; i < m; ++i) {
      short8 an;
      if (i + 1 < m) an = Abase[(size_t)(u0 + i + 1) * 64];
      aH = __builtin_amdgcn_mfma_f32_16x16x32_bf16(a, bsh[i][lane], aH, 0, 0, 0);
      if (u0 + i < nL)
        aL = __builtin_amdgcn_mfma_f32_16x16x32_bf16(a, bsh[16 + i][lane], aL, 0, 0, 0);
      a = an;
    }
    __syncthreads();
  }
  float D0 = Dp[0];
  int tt = lane & 15, rq = (lane >> 4) << 2;
#pragma unroll
  for (int r = 0; r < 4; ++r) {
    int bb = bt * 16 + rq + r;
    size_t oL = (size_t)bb * L + jL * 16 + tt;
    size_t oH = (size_t)bb * L + jH * 16 + tt;
    Y[oL] = aL[r] + D0 * X[oL];
    Y[oH] = aH[r] + D0 * X[oH];
  }
}

extern "C" void kernel_launch(void* const* d_in, const int* in_sizes, int n_in,
                              void* d_out, int out_size, void* d_ws, size_t ws_size,
                              hipStream_t stream) {
  const float* X  = (const float*)d_in[0];
  const float* A  = (const float*)d_in[1];
  const float* Bm = (const float*)d_in[2];
  const float* C  = (const float*)d_in[3];
  const float* D  = (const float*)d_in[4];
  const float* ld = (const float*)d_in[5];
  float* Y = (float*)d_out;

  float* ws = (float*)d_ws;
  unsigned* bar = (unsigned*)ws;        // 64 u32
  float* kv  = ws + 64;                 // 8192
  float* Vtr = ws + 8256;               // 128*512
  float* W   = ws + 73792;              // 64*512
  float* Xi  = ws + 106560;             // 512*512
  float* U1  = ws + 368704;             // 4*64*64
  float* U2  = ws + 385088;             // 2*128*128
  float* U3  = ws + 417856;             // 256*256
  float* PB  = ws + 483392;             // 12*512*512
  unsigned* Atab = (unsigned*)(ws + 3629120);   // 1MB
  unsigned* Btab = (unsigned*)(ws + 3891264);   // 512KB

  hipMemsetAsync(bar, 0, 64 * sizeof(unsigned), stream);
  k_chain<<<168, 256, 0, stream>>>(A, Bm, C, ld, X, Xi, U1, U2, U3, PB, Vtr, W, kv,
                                   Atab, Btab, bar);
  k_convmm<<<256, 256, 0, stream>>>((const short8*)Atab, (const short8*)Btab, X, D, Y);
}